// Round 17
// baseline (621.352 us; speedup 1.0000x reference)
//
#include <hip/hip_runtime.h>
#include <math.h>

// Problem constants (fixed by the reference)
#define BATCH 2
#define T_LEN 2048
#define D_DIM 1024
#define KSEL  15
#define HIDN  64
#define NCAND 20

typedef short  bf16x8 __attribute__((ext_vector_type(8)));
typedef float  f32x4v __attribute__((ext_vector_type(4)));

__device__ __forceinline__ float geluf(float x) {
  return 0.5f * x * (1.0f + erff(x * 0.70710678118654752440f));
}

__device__ __forceinline__ unsigned short f32_to_bf16_rne(float x) {
  unsigned u = __builtin_bit_cast(unsigned, x);
  unsigned lsb = (u >> 16) & 1u;
  u += 0x7fffu + lsb;
  return (unsigned short)(u >> 16);
}
__device__ __forceinline__ float bf16_to_f32(unsigned short h) {
  unsigned u = ((unsigned)h) << 16;
  return __builtin_bit_cast(float, u);
}

// ---------------------------------------------------------------------------
// x -> 3 bf16 planes (h, m, l): x ~= h + m + l to ~2^-27 relative.
// ---------------------------------------------------------------------------
__global__ void __launch_bounds__(256) xsplit3(const float* __restrict__ X,
                                               unsigned short* __restrict__ H,
                                               unsigned short* __restrict__ M,
                                               unsigned short* __restrict__ L)
{
  const size_t i = ((size_t)blockIdx.x * 256 + threadIdx.x) * 4;
  float4 v = *(const float4*)(X + i);
  ushort4 h, m, l;
  float r;
  h.x = f32_to_bf16_rne(v.x); r = v.x - bf16_to_f32(h.x);
  m.x = f32_to_bf16_rne(r);   l.x = f32_to_bf16_rne(r - bf16_to_f32(m.x));
  h.y = f32_to_bf16_rne(v.y); r = v.y - bf16_to_f32(h.y);
  m.y = f32_to_bf16_rne(r);   l.y = f32_to_bf16_rne(r - bf16_to_f32(m.y));
  h.z = f32_to_bf16_rne(v.z); r = v.z - bf16_to_f32(h.z);
  m.z = f32_to_bf16_rne(r);   l.z = f32_to_bf16_rne(r - bf16_to_f32(m.z));
  h.w = f32_to_bf16_rne(v.w); r = v.w - bf16_to_f32(h.w);
  m.w = f32_to_bf16_rne(r);   l.w = f32_to_bf16_rne(r - bf16_to_f32(m.w));
  *(ushort4*)(H + i) = h;
  *(ushort4*)(M + i) = m;
  *(ushort4*)(L + i) = l;
}

// ---------------------------------------------------------------------------
// W (K x N, z picks Wi/Wp) -> transposed (N x K) 3 bf16 planes.
// ---------------------------------------------------------------------------
__global__ void __launch_bounds__(256) wsplit3T(const float* __restrict__ Wi,
                                                const float* __restrict__ Wp,
                                                unsigned short* __restrict__ WT)
{
  __shared__ float tile[64][65];
  const int k0 = blockIdx.y << 6, n0 = blockIdx.x << 6;
  const int z = blockIdx.z;
  const float* W = z ? Wp : Wi;
  unsigned short* H = WT + (size_t)z * 3 * 1024 * 1024;
  unsigned short* M = H + (size_t)1024 * 1024;
  unsigned short* L = M + (size_t)1024 * 1024;
  const int tid = threadIdx.x;
  for (int idx = tid; idx < 4096; idx += 256) {
    int r = idx >> 6, c = idx & 63;
    tile[r][c] = W[(size_t)(k0 + r) * D_DIM + n0 + c];
  }
  __syncthreads();
  for (int idx = tid; idx < 4096; idx += 256) {
    int n = idx >> 6, k = idx & 63;
    float v = tile[k][n];
    unsigned short h = f32_to_bf16_rne(v);
    float r1 = v - bf16_to_f32(h);
    unsigned short m = f32_to_bf16_rne(r1);
    unsigned short l = f32_to_bf16_rne(r1 - bf16_to_f32(m));
    size_t o = (size_t)(n0 + n) * D_DIM + k0 + k;
    H[o] = h; M[o] = m; L[o] = l;
  }
}

// ---------------------------------------------------------------------------
// 3-plane split-bf16 MFMA GEMM for I = x@Wi (z=0), P = x@Wp (z=1).
// (r14/r15, unchanged.)
// ---------------------------------------------------------------------------
__global__ void __launch_bounds__(256) gemm3bf(
    const unsigned short* __restrict__ Xh, const unsigned short* __restrict__ Xm,
    const unsigned short* __restrict__ Xl, const unsigned short* __restrict__ WT,
    float* __restrict__ C)
{
  const int m0 = blockIdx.y << 6, n0 = blockIdx.x << 6;
  const int z = blockIdx.z;
  const unsigned short* BhT = WT + (size_t)z * 3 * 1024 * 1024;
  const unsigned short* BmT = BhT + (size_t)1024 * 1024;
  const unsigned short* BlT = BmT + (size_t)1024 * 1024;
  C += (size_t)z * 4096 * 1024;
  const int N = D_DIM, K = D_DIM;

  const int tid = threadIdx.x;
  const int w = tid >> 6, lane = tid & 63;
  const int kg = lane >> 4, lm = lane & 15;
  const int am0 = (w & 1) << 5;
  const int bn0 = (w >> 1) << 5;

  __shared__ unsigned short Ah[2][64][40], Am[2][64][40], Al[2][64][40];
  __shared__ unsigned short Bh[2][64][40], Bm[2][64][40], Bl[2][64][40];

  bf16x8 ones;
#pragma unroll
  for (int e = 0; e < 8; ++e) ones[e] = (short)0x3F80;

  for (int idx = tid; idx < 2048; idx += 256) {
    Ah[0][idx >> 5][idx & 31] = f32_to_bf16_rne((float)(idx >> 5));
    Bh[0][idx >> 5][idx & 31] = f32_to_bf16_rne((float)(idx >> 5));
  }
  __syncthreads();
  int mr[4], nc[4];
  {
    bf16x8 pa = *(const bf16x8*)&Ah[0][am0 + lm][kg << 3];
    bf16x8 pb = *(const bf16x8*)&Bh[0][bn0 + lm][kg << 3];
    f32x4v d1 = {0.f, 0.f, 0.f, 0.f}, d2 = {0.f, 0.f, 0.f, 0.f};
    d1 = __builtin_amdgcn_mfma_f32_16x16x32_bf16(pa, ones, d1, 0, 0, 0);
    d2 = __builtin_amdgcn_mfma_f32_16x16x32_bf16(ones, pb, d2, 0, 0, 0);
#pragma unroll
    for (int e = 0; e < 4; ++e) {
      mr[e] = ((int)d1[e]) >> 5;
      nc[e] = ((int)d2[e]) >> 5;
    }
  }
  __syncthreads();

  f32x4v ch[2][2], cm[2][2], cl[2][2];
#pragma unroll
  for (int i = 0; i < 2; ++i)
#pragma unroll
    for (int j = 0; j < 2; ++j) {
      ch[i][j] = (f32x4v){0.f, 0.f, 0.f, 0.f};
      cm[i][j] = (f32x4v){0.f, 0.f, 0.f, 0.f};
      cl[i][j] = (f32x4v){0.f, 0.f, 0.f, 0.f};
    }

  const int ar = tid >> 2, ak8 = (tid & 3) << 3;

  bf16x8 rah, ram, ral, rbh, rbm, rbl;

  {
    size_t ao = (size_t)(m0 + ar) * K + ak8;
    size_t bo = (size_t)(n0 + ar) * K + ak8;
    rah = *(const bf16x8*)(Xh + ao); ram = *(const bf16x8*)(Xm + ao);
    ral = *(const bf16x8*)(Xl + ao);
    rbh = *(const bf16x8*)(BhT + bo); rbm = *(const bf16x8*)(BmT + bo);
    rbl = *(const bf16x8*)(BlT + bo);
  }
  *(bf16x8*)&Ah[0][ar][ak8] = rah;
  *(bf16x8*)&Am[0][ar][ak8] = ram;
  *(bf16x8*)&Al[0][ar][ak8] = ral;
  *(bf16x8*)&Bh[0][ar][ak8] = rbh;
  *(bf16x8*)&Bm[0][ar][ak8] = rbm;
  *(bf16x8*)&Bl[0][ar][ak8] = rbl;
  __syncthreads();

  int buf = 0;
  for (int k0 = 0; k0 < K; k0 += 32) {
    const bool more = (k0 + 32) < K;
    if (more) {
      const int kn = k0 + 32;
      size_t ao = (size_t)(m0 + ar) * K + kn + ak8;
      size_t bo = (size_t)(n0 + ar) * K + kn + ak8;
      rah = *(const bf16x8*)(Xh + ao); ram = *(const bf16x8*)(Xm + ao);
      ral = *(const bf16x8*)(Xl + ao);
      rbh = *(const bf16x8*)(BhT + bo); rbm = *(const bf16x8*)(BmT + bo);
      rbl = *(const bf16x8*)(BlT + bo);
    }
    {
      bf16x8 a_h[2], a_m[2], a_l[2], b_h[2], b_m[2], b_l[2];
#pragma unroll
      for (int i = 0; i < 2; ++i) {
        const int rrow = am0 + (i << 4) + lm;
        a_h[i] = *(const bf16x8*)&Ah[buf][rrow][kg << 3];
        a_m[i] = *(const bf16x8*)&Am[buf][rrow][kg << 3];
        a_l[i] = *(const bf16x8*)&Al[buf][rrow][kg << 3];
        const int nrow = bn0 + (i << 4) + lm;
        b_h[i] = *(const bf16x8*)&Bh[buf][nrow][kg << 3];
        b_m[i] = *(const bf16x8*)&Bm[buf][nrow][kg << 3];
        b_l[i] = *(const bf16x8*)&Bl[buf][nrow][kg << 3];
      }
#pragma unroll
      for (int i = 0; i < 2; ++i)
#pragma unroll
        for (int j = 0; j < 2; ++j) {
          ch[i][j] = __builtin_amdgcn_mfma_f32_16x16x32_bf16(a_h[i], b_h[j], ch[i][j], 0, 0, 0);
          cm[i][j] = __builtin_amdgcn_mfma_f32_16x16x32_bf16(a_h[i], b_m[j], cm[i][j], 0, 0, 0);
          cm[i][j] = __builtin_amdgcn_mfma_f32_16x16x32_bf16(a_m[i], b_h[j], cm[i][j], 0, 0, 0);
          cl[i][j] = __builtin_amdgcn_mfma_f32_16x16x32_bf16(a_h[i], b_l[j], cl[i][j], 0, 0, 0);
          cl[i][j] = __builtin_amdgcn_mfma_f32_16x16x32_bf16(a_m[i], b_m[j], cl[i][j], 0, 0, 0);
          cl[i][j] = __builtin_amdgcn_mfma_f32_16x16x32_bf16(a_l[i], b_h[j], cl[i][j], 0, 0, 0);
        }
    }
    if (more) {
      const int nb = buf ^ 1;
      *(bf16x8*)&Ah[nb][ar][ak8] = rah;
      *(bf16x8*)&Am[nb][ar][ak8] = ram;
      *(bf16x8*)&Al[nb][ar][ak8] = ral;
      *(bf16x8*)&Bh[nb][ar][ak8] = rbh;
      *(bf16x8*)&Bm[nb][ar][ak8] = rbm;
      *(bf16x8*)&Bl[nb][ar][ak8] = rbl;
    }
    __syncthreads();
    buf ^= 1;
  }

#pragma unroll
  for (int i = 0; i < 2; ++i)
#pragma unroll
    for (int j = 0; j < 2; ++j)
#pragma unroll
      for (int e = 0; e < 4; ++e) {
        const int rrow = m0 + mr[e] + (i << 4);
        const int ccol = n0 + nc[e] + (j << 4);
        float v = (ch[i][j][e] + cm[i][j][e]) + cl[i][j][e];
        C[(size_t)rrow * N + ccol] = v;
      }
}

// ---------------------------------------------------------------------------
// PREP (fused): trig table (EXACT reference f32 bits — selection-critical)
// + palette transpose.
// ---------------------------------------------------------------------------
__global__ void __launch_bounds__(256) prep_kernel(float2* __restrict__ tab,
                                                   const float* __restrict__ pal,
                                                   float* __restrict__ palT)
{
  const int b = blockIdx.x;
  if (b < T_LEN) {
    const int t = b;
    for (int j = threadIdx.x; j < 512; j += 256) {
      double e = (double)j * (1.0 / 512.0);
      float pf = (float)pow(10000.0, e);
      float invf = 1.0f / pf;
      float angf = (float)t * invf;
      double s64, c64;
      sincos((double)angf, &s64, &c64);
      tab[(size_t)t * 512 + j] = make_float2((float)c64, (float)s64);
    }
  } else {
    const int bb = b - T_LEN;
    const int c = bb & 255, dg = bb >> 8;
    const int d = dg * 256 + threadIdx.x;
    palT[(size_t)c * D_DIM + d] = pal[(size_t)d * 256 + c];
  }
}

// ---------------------------------------------------------------------------
// RoPE in place + row L2 norms + bf16 hi planes Ih/Ph (fused emit).
// f32 rotation math unchanged — selection-critical.
// ---------------------------------------------------------------------------
__global__ void __launch_bounds__(256) rope_norm_kernel(
    float* __restrict__ bI, float* __restrict__ bP,
    const float2* __restrict__ tab,
    float* __restrict__ nI, float* __restrict__ nP,
    unsigned short* __restrict__ Ih, unsigned short* __restrict__ Ph)
{
  const int row = blockIdx.x;
  const int t = row & (T_LEN - 1);
  const int tid = threadIdx.x;
  __shared__ double redI[4], redP[4];
  double ssI = 0.0, ssP = 0.0;
  const size_t off = (size_t)row * D_DIM;
  for (int j = tid; j < 512; j += 256) {
    float2 cs = tab[(size_t)t * 512 + j];
    float c = cs.x, s = cs.y;

    float a1 = bI[off + j], a2 = bI[off + 512 + j];
    float o1 = __fsub_rn(__fmul_rn(a1, c), __fmul_rn(a2, s));
    float o2 = __fadd_rn(__fmul_rn(a1, s), __fmul_rn(a2, c));
    bI[off + j] = o1; bI[off + 512 + j] = o2;
    Ih[off + j] = f32_to_bf16_rne(o1); Ih[off + 512 + j] = f32_to_bf16_rne(o2);
    ssI += (double)o1 * o1 + (double)o2 * o2;

    float p1 = bP[off + j], p2 = bP[off + 512 + j];
    float q1 = __fsub_rn(__fmul_rn(p1, c), __fmul_rn(p2, s));
    float q2 = __fadd_rn(__fmul_rn(p1, s), __fmul_rn(p2, c));
    bP[off + j] = q1; bP[off + 512 + j] = q2;
    Ph[off + j] = f32_to_bf16_rne(q1); Ph[off + 512 + j] = f32_to_bf16_rne(q2);
    ssP += (double)q1 * q1 + (double)q2 * q2;
  }
#pragma unroll
  for (int o = 32; o >= 1; o >>= 1) { ssI += __shfl_xor(ssI, o); ssP += __shfl_xor(ssP, o); }
  if ((tid & 63) == 0) { redI[tid >> 6] = ssI; redP[tid >> 6] = ssP; }
  __syncthreads();
  if (tid == 0) {
    nI[row] = fmaxf((float)sqrt(redI[0] + redI[1] + redI[2] + redI[3]), 1e-12f);
    nP[row] = fmaxf((float)sqrt(redP[0] + redP[1] + redP[2] + redP[3]), 1e-12f);
  }
}

// ---------------------------------------------------------------------------
// bf16 SCREEN for S (candidates only; exact rescore follows). (unchanged.)
// ---------------------------------------------------------------------------
__global__ void __launch_bounds__(256) screen_bf16(
    const unsigned short* __restrict__ Ih, const unsigned short* __restrict__ Ph,
    unsigned short* __restrict__ Ssc)
{
  int rem = blockIdx.x, bi = 0;
  while (rem >= (bi >> 1) + 1) { rem -= (bi >> 1) + 1; ++bi; }
  const int m0 = bi << 6, n0 = rem << 7;
  const int z = blockIdx.z;
  const unsigned short* A = Ih + (size_t)z * T_LEN * D_DIM;
  const unsigned short* B = Ph + (size_t)z * T_LEN * D_DIM;
  unsigned short* C = Ssc + (size_t)z * T_LEN * T_LEN;
  const int N = T_LEN, K = D_DIM;

  const int tid = threadIdx.x;
  const int w = tid >> 6, lane = tid & 63;
  const int kg = lane >> 4, lm = lane & 15;
  const int am0 = (w & 1) << 5;
  const int bn0 = (w >> 1) << 6;

  __shared__ unsigned short As_h[2][64][40];
  __shared__ unsigned short Bs_h[2][128][40];

  bf16x8 ones;
#pragma unroll
  for (int e = 0; e < 8; ++e) ones[e] = (short)0x3F80;

  for (int idx = tid; idx < 2048; idx += 256)
    As_h[0][idx >> 5][idx & 31] = f32_to_bf16_rne((float)(idx >> 5));
  for (int idx = tid; idx < 4096; idx += 256)
    Bs_h[0][idx >> 5][idx & 31] = f32_to_bf16_rne((float)(idx >> 5));
  __syncthreads();
  int mr[4], nc[4];
  {
    bf16x8 pa = *(const bf16x8*)&As_h[0][am0 + lm][kg << 3];
    bf16x8 pb = *(const bf16x8*)&Bs_h[0][bn0 + lm][kg << 3];
    f32x4v d1 = {0.f, 0.f, 0.f, 0.f}, d2 = {0.f, 0.f, 0.f, 0.f};
    d1 = __builtin_amdgcn_mfma_f32_16x16x32_bf16(pa, ones, d1, 0, 0, 0);
    d2 = __builtin_amdgcn_mfma_f32_16x16x32_bf16(ones, pb, d2, 0, 0, 0);
#pragma unroll
    for (int e = 0; e < 4; ++e) {
      mr[e] = ((int)d1[e]) >> 5;
      nc[e] = ((int)d2[e]) >> 5;
    }
  }
  __syncthreads();

  f32x4v c00 = {0,0,0,0}, c01 = {0,0,0,0}, c02 = {0,0,0,0}, c03 = {0,0,0,0};
  f32x4v c10 = {0,0,0,0}, c11 = {0,0,0,0}, c12 = {0,0,0,0}, c13 = {0,0,0,0};

  const int ar  = tid >> 2, ak8 = (tid & 3) << 3;
  const int bna = tid >> 2, bnb = 64 + (tid >> 2), bk8 = (tid & 3) << 3;

  bf16x8 ra, rb0, rb1;

  ra  = *(const bf16x8*)(A + (size_t)(m0 + ar) * K + ak8);
  rb0 = *(const bf16x8*)(B + (size_t)(n0 + bna) * K + bk8);
  rb1 = *(const bf16x8*)(B + (size_t)(n0 + bnb) * K + bk8);
  *(bf16x8*)&As_h[0][ar][ak8]  = ra;
  *(bf16x8*)&Bs_h[0][bna][bk8] = rb0;
  *(bf16x8*)&Bs_h[0][bnb][bk8] = rb1;
  __syncthreads();

  int buf = 0;
  for (int k0 = 0; k0 < K; k0 += 32) {
    const bool more = (k0 + 32) < K;
    if (more) {
      const int kn = k0 + 32;
      ra  = *(const bf16x8*)(A + (size_t)(m0 + ar) * K + kn + ak8);
      rb0 = *(const bf16x8*)(B + (size_t)(n0 + bna) * K + kn + bk8);
      rb1 = *(const bf16x8*)(B + (size_t)(n0 + bnb) * K + kn + bk8);
    }
    {
      bf16x8 a0 = *(const bf16x8*)&As_h[buf][am0 + lm][kg << 3];
      bf16x8 a1 = *(const bf16x8*)&As_h[buf][am0 + 16 + lm][kg << 3];
      bf16x8 b0 = *(const bf16x8*)&Bs_h[buf][bn0 + lm][kg << 3];
      bf16x8 b1 = *(const bf16x8*)&Bs_h[buf][bn0 + 16 + lm][kg << 3];
      bf16x8 b2 = *(const bf16x8*)&Bs_h[buf][bn0 + 32 + lm][kg << 3];
      bf16x8 b3 = *(const bf16x8*)&Bs_h[buf][bn0 + 48 + lm][kg << 3];
      c00 = __builtin_amdgcn_mfma_f32_16x16x32_bf16(a0, b0, c00, 0, 0, 0);
      c01 = __builtin_amdgcn_mfma_f32_16x16x32_bf16(a0, b1, c01, 0, 0, 0);
      c02 = __builtin_amdgcn_mfma_f32_16x16x32_bf16(a0, b2, c02, 0, 0, 0);
      c03 = __builtin_amdgcn_mfma_f32_16x16x32_bf16(a0, b3, c03, 0, 0, 0);
      c10 = __builtin_amdgcn_mfma_f32_16x16x32_bf16(a1, b0, c10, 0, 0, 0);
      c11 = __builtin_amdgcn_mfma_f32_16x16x32_bf16(a1, b1, c11, 0, 0, 0);
      c12 = __builtin_amdgcn_mfma_f32_16x16x32_bf16(a1, b2, c12, 0, 0, 0);
      c13 = __builtin_amdgcn_mfma_f32_16x16x32_bf16(a1, b3, c13, 0, 0, 0);
    }
    if (more) {
      const int nb = buf ^ 1;
      *(bf16x8*)&As_h[nb][ar][ak8]  = ra;
      *(bf16x8*)&Bs_h[nb][bna][bk8] = rb0;
      *(bf16x8*)&Bs_h[nb][bnb][bk8] = rb1;
    }
    __syncthreads();
    buf ^= 1;
  }

#pragma unroll
  for (int e = 0; e < 4; ++e) {
    const size_t r0 = (size_t)(m0 + mr[e]) * N;
    const size_t r1 = r0 + (size_t)16 * N;
    const int c = n0 + nc[e];
    C[r0 + c +  0] = f32_to_bf16_rne(c00[e]);
    C[r0 + c + 16] = f32_to_bf16_rne(c01[e]);
    C[r0 + c + 32] = f32_to_bf16_rne(c02[e]);
    C[r0 + c + 48] = f32_to_bf16_rne(c03[e]);
    C[r1 + c +  0] = f32_to_bf16_rne(c10[e]);
    C[r1 + c + 16] = f32_to_bf16_rne(c11[e]);
    C[r1 + c + 32] = f32_to_bf16_rne(c12[e]);
    C[r1 + c + 48] = f32_to_bf16_rne(c13[e]);
  }
}

// ---------------------------------------------------------------------------
// Top-NCAND screen candidates per causal row (bf16 S). -1 = invalid.
// ---------------------------------------------------------------------------
__global__ void __launch_bounds__(256) topk_screen(const unsigned short* __restrict__ Ssc,
                                                   int* __restrict__ cand)
{
  const int b = blockIdx.y;
  const unsigned short* S = Ssc + (size_t)b * T_LEN * T_LEN;
  const int wave = threadIdx.x >> 6, lane = threadIdx.x & 63;
  const int t = blockIdx.x * 4 + wave;
  const unsigned short* rowp = S + (size_t)t * T_LEN;
  float v[32];
#pragma unroll
  for (int i = 0; i < 32; ++i) {
    int s = lane + (i << 6);
    v[i] = (s <= t) ? bf16_to_f32(rowp[s]) : -INFINITY;
  }
  float pv = INFINITY; int pidx = -1;
  int* outp = cand + ((size_t)b * T_LEN + t) * NCAND;
  for (int k = 0; k < NCAND; ++k) {
    float bv = -INFINITY; int bi = 0x7fffffff;
#pragma unroll
    for (int i = 0; i < 32; ++i) {
      int s = lane + (i << 6);
      float vv = v[i];
      bool elig = (vv < pv) || (vv == pv && s > pidx);
      if (elig && vv > bv) { bv = vv; bi = s; }
    }
#pragma unroll
    for (int o = 32; o >= 1; o >>= 1) {
      float ov = __shfl_xor(bv, o);
      int oi = __shfl_xor(bi, o);
      if (ov > bv || (ov == bv && oi < bi)) { bv = ov; bi = oi; }
    }
    pv = bv; pidx = bi;
    if (lane == 0) outp[k] = (bi == 0x7fffffff || bv == -INFINITY) ? -1 : bi;
  }
}

// ---------------------------------------------------------------------------
// Exact rescore: f64 dot of I_t with each candidate P row (f32 arrays),
// rounded to f32 after the 2^-5 scale, tie -> lower index, top-15 -> idx.
// ---------------------------------------------------------------------------
__global__ void __launch_bounds__(256) rescore_kernel(
    const float* __restrict__ I, const float* __restrict__ P,
    const int* __restrict__ cand, int* __restrict__ idx)
{
  const int row = blockIdx.x;
  const int base = row & ~(T_LEN - 1);
  const int tid = threadIdx.x;
  const int w = tid >> 6, lane = tid & 63;

  __shared__ float valS[NCAND];
  __shared__ int   sidxS[NCAND];
  __shared__ int   candS[NCAND];

  if (tid < NCAND) candS[tid] = cand[(size_t)row * NCAND + tid];
  __syncthreads();

  double iv[16];
  const float* irow = I + (size_t)row * D_DIM;
#pragma unroll
  for (int j = 0; j < 16; ++j) iv[j] = (double)irow[lane + (j << 6)];

  for (int c = w; c < NCAND; c += 4) {
    int s = candS[c];
    double acc = 0.0;
    if (s >= 0) {
      const float* prow = P + ((size_t)base + s) * D_DIM;
#pragma unroll
      for (int j = 0; j < 16; ++j)
        acc = fma(iv[j], (double)prow[lane + (j << 6)], acc);
    }
#pragma unroll
    for (int o = 32; o >= 1; o >>= 1) acc += __shfl_xor(acc, o);
    if (lane == 0) {
      valS[c] = (s >= 0) ? (float)(acc * 0.03125) : -INFINITY;
      sidxS[c] = s;
    }
  }
  __syncthreads();
  if (tid == 0) {
    bool taken[NCAND];
#pragma unroll
    for (int c = 0; c < NCAND; ++c) taken[c] = false;
    int* outp = idx + (size_t)row * 16;
    for (int k = 0; k < KSEL; ++k) {
      float best = -INFINITY; int bidx = 0x7fffffff; int bc = -1;
      for (int c = 0; c < NCAND; ++c) {
        if (taken[c] || sidxS[c] < 0) continue;
        float v = valS[c];
        if (v > best || (v == best && sidxS[c] < bidx)) { best = v; bidx = sidxS[c]; bc = c; }
      }
      if (bc >= 0) { taken[bc] = true; outp[k] = bidx; }
      else outp[k] = 0;
    }
  }
}

// ---------------------------------------------------------------------------
// Wo (K x N) -> transposed bf16 hi/lo planes (N x K). After rescore (P dead).
// ---------------------------------------------------------------------------
__global__ void __launch_bounds__(256) woconvT(const float* __restrict__ Wo,
                                               unsigned short* __restrict__ HT,
                                               unsigned short* __restrict__ LT)
{
  __shared__ float tile[64][65];
  const int k0 = blockIdx.y << 6, n0 = blockIdx.x << 6;
  const int tid = threadIdx.x;
  for (int idx = tid; idx < 4096; idx += 256) {
    int r = idx >> 6, c = idx & 63;
    tile[r][c] = Wo[(size_t)(k0 + r) * D_DIM + n0 + c];
  }
  __syncthreads();
  for (int idx = tid; idx < 4096; idx += 256) {
    int n = idx >> 6, k = idx & 63;
    float v = tile[k][n];
    unsigned short h = f32_to_bf16_rne(v);
    HT[(size_t)(n0 + n) * D_DIM + k0 + k] = h;
    LT[(size_t)(n0 + n) * D_DIM + k0 + k] = f32_to_bf16_rne(v - bf16_to_f32(h));
  }
}

// ---------------------------------------------------------------------------
// Per-(b,t), WAVE-PER-ROW: gram via 4-accumulator MFMA chains (dependency
// depth 32 -> 8) + FIXED-TRIP (60) fully-unrolled palette blend so the 60
// palT loads per d batch-issue instead of serializing on L2 latency (this
// was the r16 bottleneck: runtime-bound inner loop -> 60 x ~200cyc chains).
// ---------------------------------------------------------------------------
__global__ void __launch_bounds__(256) relmlp_kernel(
    const unsigned short* __restrict__ Ih, const unsigned short* __restrict__ Ph,
    const float* __restrict__ nI, const float* __restrict__ nP,
    const int* __restrict__ topk,
    const float* __restrict__ W1, const float* __restrict__ b1,
    const float* __restrict__ W2, const float* __restrict__ b2,
    const float* __restrict__ Wc, const float* __restrict__ bc,
    const float* __restrict__ Wm, const float* __restrict__ bm,
    const float* __restrict__ palT,
    unsigned short* __restrict__ Vh, unsigned short* __restrict__ Vl)
{
  const int wv   = threadIdx.x >> 6;          // wave id: row owner
  const int lane = threadIdx.x & 63;
  const int row  = (blockIdx.x << 2) + wv;
  const int t    = row & (T_LEN - 1);
  const int base = row & ~(T_LEN - 1);
  const int nk   = (t + 1 < KSEL) ? (t + 1) : KSEL;

  __shared__ int   sidxS[4][16];
  __shared__ float nrmS[4][16];
  __shared__ float gS[4][16][16];
  __shared__ float relS[4][KSEL][18];
  __shared__ float h1S[4][KSEL][HIDN];
  __shared__ float h2S[4][KSEL][HIDN];
  __shared__ float mixS[4][KSEL], wSS[4][KSEL], zxS[4][KSEL], zyS[4][KSEL];
  __shared__ float coefS[4][4 * KSEL];
  __shared__ int   cellS[4][4 * KSEL];

  if (lane < 16) {
    int s = t;
    if (lane >= 1) s = (lane <= nk) ? topk[(size_t)row * 16 + (lane - 1)] : 0;
    sidxS[wv][lane] = s;
    nrmS[wv][lane] = (lane == 0) ? nI[row] : nP[base + s];
  }
  __syncthreads();

  // ---- gram: direct-global MFMA fragments, 4 independent accumulators ----
  const int lm = lane & 15, kg = lane >> 4;
  {
    const unsigned short* src = (lm == 0)
        ? (Ih + (size_t)row * D_DIM)
        : (Ph + ((size_t)base + sidxS[wv][lm]) * D_DIM);
    f32x4v acc0 = {0.f, 0.f, 0.f, 0.f}, acc1 = {0.f, 0.f, 0.f, 0.f};
    f32x4v acc2 = {0.f, 0.f, 0.f, 0.f}, acc3 = {0.f, 0.f, 0.f, 0.f};
#pragma unroll
    for (int ks = 0; ks < 32; ks += 4) {
      bf16x8 a0, a1, a2, a3;
      if (lm <= nk) {
        a0 = *(const bf16x8*)(src + ((ks + 0) << 5) + (kg << 3));
        a1 = *(const bf16x8*)(src + ((ks + 1) << 5) + (kg << 3));
        a2 = *(const bf16x8*)(src + ((ks + 2) << 5) + (kg << 3));
        a3 = *(const bf16x8*)(src + ((ks + 3) << 5) + (kg << 3));
      } else {
        bf16x8 zz = {0, 0, 0, 0, 0, 0, 0, 0};
        a0 = zz; a1 = zz; a2 = zz; a3 = zz;
      }
      acc0 = __builtin_amdgcn_mfma_f32_16x16x32_bf16(a0, a0, acc0, 0, 0, 0);
      acc1 = __builtin_amdgcn_mfma_f32_16x16x32_bf16(a1, a1, acc1, 0, 0, 0);
      acc2 = __builtin_amdgcn_mfma_f32_16x16x32_bf16(a2, a2, acc2, 0, 0, 0);
      acc3 = __builtin_amdgcn_mfma_f32_16x16x32_bf16(a3, a3, acc3, 0, 0, 0);
    }
    f32x4v acc;
#pragma unroll
    for (int e = 0; e < 4; ++e)
      acc[e] = (acc0[e] + acc1[e]) + (acc2[e] + acc3[e]);

    bf16x8 pa, ones;
    unsigned short lmb = f32_to_bf16_rne((float)lm);
#pragma unroll
    for (int e = 0; e < 8; ++e) { pa[e] = (short)lmb; ones[e] = (short)0x3F80; }
    f32x4v d1 = {0.f, 0.f, 0.f, 0.f}, d2 = {0.f, 0.f, 0.f, 0.f};
    d1 = __builtin_amdgcn_mfma_f32_16x16x32_bf16(pa, ones, d1, 0, 0, 0);
    d2 = __builtin_amdgcn_mfma_f32_16x16x32_bf16(ones, pa, d2, 0, 0, 0);
#pragma unroll
    for (int e = 0; e < 4; ++e) {
      int pi2 = ((int)d1[e]) >> 5;
      int pj2 = ((int)d2[e]) >> 5;
      float g = 0.f;
      if (pi2 <= nk && pj2 <= nk) {
        g = acc[e] / (nrmS[wv][pi2] * nrmS[wv][pj2]);
        g = fminf(fmaxf(g, -1.f), 1.f);
      }
      gS[wv][pi2][pj2] = g;
    }
  }
  __syncthreads();

  // ---- rel features ----
  for (int o = lane; o < KSEL * 17; o += 64) {
    int k = o / 17, f = o % 17;
    float v = 0.f;
    if (k < nk) {
      if (f < KSEL)        v = (f < nk) ? gS[wv][k + 1][f + 1] : 0.f;
      else if (f == KSEL)  v = gS[wv][0][k + 1];
      else                 v = (float)(t - sidxS[wv][k + 1]) * (1.0f / (float)T_LEN);
    }
    relS[wv][k][f] = v;
  }
  __syncthreads();

  // ---- MLP1: lane = output channel m ----
#pragma unroll
  for (int k = 0; k < KSEL; ++k) {
    float a = b1[lane];
#pragma unroll
    for (int f = 0; f < 17; ++f) a = fmaf(relS[wv][k][f], W1[f * HIDN + lane], a);
    h1S[wv][k][lane] = geluf(a);
  }
  __syncthreads();

  // ---- MLP2 ----
#pragma unroll
  for (int k = 0; k < KSEL; ++k) {
    float a = b2[lane];
#pragma unroll 8
    for (int n = 0; n < HIDN; ++n) a = fmaf(h1S[wv][k][n], W2[n * HIDN + lane], a);
    h2S[wv][k][lane] = geluf(a);
  }
  __syncthreads();

  // ---- heads ----
  if (lane < KSEL) {
    float a0 = 0.f, a1 = 0.f, am = 0.f;
#pragma unroll 8
    for (int n = 0; n < HIDN; ++n) {
      float h = h2S[wv][lane][n];
      a0 = fmaf(h, Wc[n * 2 + 0], a0);
      a1 = fmaf(h, Wc[n * 2 + 1], a1);
      am = fmaf(h, Wm[n], am);
    }
    zxS[wv][lane] = tanhf(a0 + bc[0]);
    zyS[wv][lane] = tanhf(a1 + bc[1]);
    mixS[wv][lane] = am + bm[0];
  }
  __syncthreads();

  // ---- softmax (lane 0 of each wave) ----
  if (lane == 0) {
    float mx = -INFINITY;
    for (int k = 0; k < nk; ++k) mx = fmaxf(mx, mixS[wv][k]);
    float ssum = 0.f;
    for (int k = 0; k < nk; ++k) { float e = expf(mixS[wv][k] - mx); wSS[wv][k] = e; ssum += e; }
    float inv = 1.f / ssum;
    for (int k = 0; k < nk; ++k) wSS[wv][k] *= inv;
  }
  __syncthreads();

  // ---- bilinear coefficients ----
  if (lane < KSEL) {
    int k = lane;
    if (k < nk) {
      float w = wSS[wv][k];
      float fx = fminf(fmaxf((zxS[wv][k] + 1.f) * 0.5f * 15.f, 0.f), 15.f);
      float fy = fminf(fmaxf((zyS[wv][k] + 1.f) * 0.5f * 15.f, 0.f), 15.f);
      int x0 = (int)floorf(fx); int x1i = (x0 + 1 < 15) ? x0 + 1 : 15;
      int y0 = (int)floorf(fy); int y1i = (y0 + 1 < 15) ? y0 + 1 : 15;
      float wx = fx - (float)x0, wy = fy - (float)y0;
      cellS[wv][k * 4 + 0] = y0 * 16 + x0;   coefS[wv][k * 4 + 0] = w * (1.f - wy) * (1.f - wx);
      cellS[wv][k * 4 + 1] = y0 * 16 + x1i;  coefS[wv][k * 4 + 1] = w * (1.f - wy) * wx;
      cellS[wv][k * 4 + 2] = y1i * 16 + x0;  coefS[wv][k * 4 + 2] = w * wy * (1.f - wx);
      cellS[wv][k * 4 + 3] = y1i * 16 + x1i; coefS[wv][k * 4 + 3] = w * wy * wx;
    } else {
      cellS[wv][k * 4 + 0] = cellS[wv][k * 4 + 1] = cellS[wv][k * 4 + 2] = cellS[wv][k * 4 + 3] = 0;
      coefS[wv][k * 4 + 0] = coefS[wv][k * 4 + 1] = coefS[wv][k * 4 + 2] = coefS[wv][k * 4 + 3] = 0.f;
    }
  }
  __syncthreads();

  // ---- palette blend: FIXED 60-trip unrolled (coef 0-padded) ----
  for (int d = lane; d < D_DIM; d += 64) {
    float a = 0.f;
#pragma unroll
    for (int j = 0; j < 4 * KSEL; ++j)
      a = fmaf(coefS[wv][j], palT[(size_t)cellS[wv][j] * D_DIM + d], a);
    unsigned short h = f32_to_bf16_rne(a);
    Vh[(size_t)row * D_DIM + d] = h;
    Vl[(size_t)row * D_DIM + d] = f32_to_bf16_rne(a - bf16_to_f32(h));
  }
}

// ---------------------------------------------------------------------------
// Split-bf16 MFMA GEMM for out = V @ Wo. (r10, unchanged.)
// ---------------------------------------------------------------------------
__global__ void __launch_bounds__(256) gemmbf(
    const unsigned short* __restrict__ Ah, const unsigned short* __restrict__ Al,
    const unsigned short* __restrict__ BhT, const unsigned short* __restrict__ BlT,
    float* __restrict__ C, int N, int K)
{
  const int m0 = blockIdx.y << 6, n0 = blockIdx.x << 7;
  const int tid = threadIdx.x;
  const int w = tid >> 6, lane = tid & 63;
  const int kg = lane >> 4, lm = lane & 15;
  const int am0 = (w & 1) << 5;
  const int bn0 = (w >> 1) << 6;

  __shared__ unsigned short As_h[2][64][40],  As_l[2][64][40];
  __shared__ unsigned short Bs_h[2][128][40], Bs_l[2][128][40];

  bf16x8 ones;
#pragma unroll
  for (int e = 0; e < 8; ++e) ones[e] = (short)0x3F80;

  for (int idx = tid; idx < 2048; idx += 256)
    As_h[0][idx >> 5][idx & 31] = f32_to_bf16_rne((float)(idx >> 5));
  for (int idx = tid; idx < 4096; idx += 256)
    Bs_h[0][idx >> 5][idx & 31] = f32_to_bf16_rne((float)(idx >> 5));
  __syncthreads();
  int mr[4], nc[4];
  {
    bf16x8 pa = *(const bf16x8*)&As_h[0][am0 + lm][kg << 3];
    bf16x8 pb = *(const bf16x8*)&Bs_h[0][bn0 + lm][kg << 3];
    f32x4v d1 = {0.f, 0.f, 0.f, 0.f}, d2 = {0.f, 0.f, 0.f, 0.f};
    d1 = __builtin_amdgcn_mfma_f32_16x16x32_bf16(pa, ones, d1, 0, 0, 0);
    d2 = __builtin_amdgcn_mfma_f32_16x16x32_bf16(ones, pb, d2, 0, 0, 0);
#pragma unroll
    for (int e = 0; e < 4; ++e) {
      mr[e] = ((int)d1[e]) >> 5;
      nc[e] = ((int)d2[e]) >> 5;
    }
  }
  __syncthreads();

  f32x4v c00 = {0,0,0,0}, c01 = {0,0,0,0}, c02 = {0,0,0,0}, c03 = {0,0,0,0};
  f32x4v c10 = {0,0,0,0}, c11 = {0,0,0,0}, c12 = {0,0,0,0}, c13 = {0,0,0,0};

  const int ar  = tid >> 2, ak8 = (tid & 3) << 3;
  const int bna = tid >> 2, bnb = 64 + (tid >> 2), bk8 = (tid & 3) << 3;

  bf16x8 rah, ral, rbh0, rbl0, rbh1, rbl1;

  rah  = *(const bf16x8*)(Ah  + (size_t)(m0 + ar) * K + ak8);
  ral  = *(const bf16x8*)(Al  + (size_t)(m0 + ar) * K + ak8);
  rbh0 = *(const bf16x8*)(BhT + (size_t)(n0 + bna) * K + bk8);
  rbl0 = *(const bf16x8*)(BlT + (size_t)(n0 + bna) * K + bk8);
  rbh1 = *(const bf16x8*)(BhT + (size_t)(n0 + bnb) * K + bk8);
  rbl1 = *(const bf16x8*)(BlT + (size_t)(n0 + bnb) * K + bk8);
  *(bf16x8*)&As_h[0][ar][ak8]  = rah;
  *(bf16x8*)&As_l[0][ar][ak8]  = ral;
  *(bf16x8*)&Bs_h[0][bna][bk8] = rbh0;
  *(bf16x8*)&Bs_l[0][bna][bk8] = rbl0;
  *(bf16x8*)&Bs_h[0][bnb][bk8] = rbh1;
  *(bf16x8*)&Bs_l[0][bnb][bk8] = rbl1;
  __syncthreads();

  int buf = 0;
  for (int k0 = 0; k0 < K; k0 += 32) {
    const bool more = (k0 + 32) < K;
    if (more) {
      const int kn = k0 + 32;
      rah  = *(const bf16x8*)(Ah  + (size_t)(m0 + ar) * K + kn + ak8);
      ral  = *(const bf16x8*)(Al  + (size_t)(m0 + ar) * K + kn + ak8);
      rbh0 = *(const bf16x8*)(BhT + (size_t)(n0 + bna) * K + kn + bk8);
      rbl0 = *(const bf16x8*)(BlT + (size_t)(n0 + bna) * K + kn + bk8);
      rbh1 = *(const bf16x8*)(BhT + (size_t)(n0 + bnb) * K + kn + bk8);
      rbl1 = *(const bf16x8*)(BlT + (size_t)(n0 + bnb) * K + kn + bk8);
    }
    {
      bf16x8 ah0 = *(const bf16x8*)&As_h[buf][am0 + lm][kg << 3];
      bf16x8 ah1 = *(const bf16x8*)&As_h[buf][am0 + 16 + lm][kg << 3];
      bf16x8 al0 = *(const bf16x8*)&As_l[buf][am0 + lm][kg << 3];
      bf16x8 al1 = *(const bf16x8*)&As_l[buf][am0 + 16 + lm][kg << 3];
      bf16x8 bh0 = *(const bf16x8*)&Bs_h[buf][bn0 + lm][kg << 3];
      bf16x8 bh1 = *(const bf16x8*)&Bs_h[buf][bn0 + 16 + lm][kg << 3];
      bf16x8 bh2 = *(const bf16x8*)&Bs_h[buf][bn0 + 32 + lm][kg << 3];
      bf16x8 bh3 = *(const bf16x8*)&Bs_h[buf][bn0 + 48 + lm][kg << 3];
      bf16x8 bl0 = *(const bf16x8*)&Bs_l[buf][bn0 + lm][kg << 3];
      bf16x8 bl1 = *(const bf16x8*)&Bs_l[buf][bn0 + 16 + lm][kg << 3];
      bf16x8 bl2 = *(const bf16x8*)&Bs_l[buf][bn0 + 32 + lm][kg << 3];
      bf16x8 bl3 = *(const bf16x8*)&Bs_l[buf][bn0 + 48 + lm][kg << 3];

      c00 = __builtin_amdgcn_mfma_f32_16x16x32_bf16(ah0, bh0, c00, 0, 0, 0);
      c01 = __builtin_amdgcn_mfma_f32_16x16x32_bf16(ah0, bh1, c01, 0, 0, 0);
      c02 = __builtin_amdgcn_mfma_f32_16x16x32_bf16(ah0, bh2, c02, 0, 0, 0);
      c03 = __builtin_amdgcn_mfma_f32_16x16x32_bf16(ah0, bh3, c03, 0, 0, 0);
      c10 = __builtin_amdgcn_mfma_f32_16x16x32_bf16(ah1, bh0, c10, 0, 0, 0);
      c11 = __builtin_amdgcn_mfma_f32_16x16x32_bf16(ah1, bh1, c11, 0, 0, 0);
      c12 = __builtin_amdgcn_mfma_f32_16x16x32_bf16(ah1, bh2, c12, 0, 0, 0);
      c13 = __builtin_amdgcn_mfma_f32_16x16x32_bf16(ah1, bh3, c13, 0, 0, 0);

      c00 = __builtin_amdgcn_mfma_f32_16x16x32_bf16(ah0, bl0, c00, 0, 0, 0);
      c01 = __builtin_amdgcn_mfma_f32_16x16x32_bf16(ah0, bl1, c01, 0, 0, 0);
      c02 = __builtin_amdgcn_mfma_f32_16x16x32_bf16(ah0, bl2, c02, 0, 0, 0);
      c03 = __builtin_amdgcn_mfma_f32_16x16x32_bf16(ah0, bl3, c03, 0, 0, 0);
      c10 = __builtin_amdgcn_mfma_f32_16x16x32_bf16(ah1, bl0, c10, 0, 0, 0);
      c11 = __builtin_amdgcn_mfma_f32_16x16x32_bf16(ah1, bl1, c11, 0, 0, 0);
      c12 = __builtin_amdgcn_mfma_f32_16x16x32_bf16(ah1, bl2, c12, 0, 0, 0);
      c13 = __builtin_amdgcn_mfma_f32_16x16x32_bf16(ah1, bl3, c13, 0, 0, 0);

      c00 = __builtin_amdgcn_mfma_f32_16x16x32_bf16(al0, bh0, c00, 0, 0, 0);
      c01 = __builtin_amdgcn_mfma_f32_16x16x32_bf16(al0, bh1, c01, 0, 0, 0);
      c02 = __builtin_amdgcn_mfma_f32_16x16x32_bf16(al0, bh2, c02, 0, 0, 0);
      c03 = __builtin_amdgcn_mfma_f32_16x16x32_bf16(al0, bh3, c03, 0, 0, 0);
      c10 = __builtin_amdgcn_mfma_f32_16x16x32_bf16(al1, bh0, c10, 0, 0, 0);
      c11 = __builtin_amdgcn_mfma_f32_16x16x32_bf16(al1, bh1, c11, 0, 0, 0);
      c12 = __builtin_amdgcn_mfma_f32_16x16x32_bf16(al1, bh2, c12, 0, 0, 0);
      c13 = __builtin_amdgcn_mfma_f32_16x16x32_bf16(al1, bh3, c13, 0, 0, 0);
    }
    if (more) {
      const int nb = buf ^ 1;
      *(bf16x8*)&As_h[nb][ar][ak8]  = rah;
      *(bf16x8*)&As_l[nb][ar][ak8]  = ral;
      *(bf16x8*)&Bs_h[nb][bna][bk8] = rbh0;
      *(bf16x8*)&Bs_l[nb][bna][bk8] = rbl0;
      *(bf16x8*)&Bs_h[nb][bnb][bk8] = rbh1;
      *(bf16x8*)&Bs_l[nb][bnb][bk8] = rbl1;
    }
    __syncthreads();
    buf ^= 1;
  }

#pragma unroll
  for (int e = 0; e < 4; ++e) {
    const size_t r0 = (size_t)(m0 + mr[e]) * N;
    const size_t r1 = r0 + (size_t)16 * N;
    const int c = n0 + nc[e];
    C[r0 + c +  0] = c00[e];
    C[r0 + c + 16] = c01[e];
    C[r0 + c + 32] = c02[e];
    C[r0 + c + 48] = c03[e];
    C[r1 + c +  0] = c10[e];
    C[r1 + c + 16] = c11[e];
    C[r1 + c + 32] = c12[e];
    C[r1 + c + 48] = c13[e];
  }
}

// ---------------------------------------------------------------------------
// Host launcher. (r16 structure, unchanged.)
// ---------------------------------------------------------------------------
extern "C" void kernel_launch(void* const* d_in, const int* in_sizes, int n_in,
                              void* d_out, int out_size, void* d_ws, size_t ws_size,
                              hipStream_t stream)
{
  (void)in_sizes; (void)n_in; (void)out_size; (void)ws_size;
  const float* x   = (const float*)d_in[0];
  const float* Wi  = (const float*)d_in[1];
  const float* Wp  = (const float*)d_in[2];
  const float* pal = (const float*)d_in[3];
  const float* W1  = (const float*)d_in[4];
  const float* b1  = (const float*)d_in[5];
  const float* W2  = (const float*)d_in[6];
  const float* b2  = (const float*)d_in[7];
  const float* Wc  = (const float*)d_in[8];
  const float* bc  = (const float*)d_in[9];
  const float* Wm  = (const float*)d_in[10];
  const float* bm  = (const float*)d_in[11];
  const float* Wo  = (const float*)d_in[12];
  float* out = (float*)d_out;

  float* w = (float*)d_ws;
  float* palT = w;  w += (size_t)256 * D_DIM;
  float* I    = w;  w += (size_t)BATCH * T_LEN * D_DIM;
  float* P    = w;  w += (size_t)BATCH * T_LEN * D_DIM;
  float* Sb   = w;  w += (size_t)BATCH * T_LEN * T_LEN;
  float* nIb  = w;  w += (size_t)BATCH * T_LEN;
  float* nPb  = w;  w += (size_t)BATCH * T_LEN;
  int*   idx  = (int*)w;  w += (size_t)BATCH * T_LEN * 16;
  int*   cand = (int*)w;

  unsigned short* Xh = (unsigned short*)Sb;
  unsigned short* Xm = Xh + (size_t)4096 * 1024;
  unsigned short* Xl = Xm + (size_t)4096 * 1024;
  unsigned short* WT = (unsigned short*)d_out;

  float2* tab = (float2*)Sb;
  unsigned short* Ssc = (unsigned short*)Sb;
  unsigned short* Ih  = (unsigned short*)(Sb + (size_t)4 * 1024 * 1024);
  unsigned short* Ph  = Ih + (size_t)4 * 1024 * 1024;
  unsigned short* Vh  = (unsigned short*)Sb;
  unsigned short* Vl  = Vh + (size_t)4 * 1024 * 1024;
  unsigned short* WohT = (unsigned short*)P;
  unsigned short* WolT = WohT + (size_t)D_DIM * D_DIM;

  const int MROWS = BATCH * T_LEN;  // 4096

  xsplit3<<<(MROWS * D_DIM) / (256 * 4), 256, 0, stream>>>(x, Xh, Xm, Xl);
  wsplit3T<<<dim3(D_DIM / 64, D_DIM / 64, 2), 256, 0, stream>>>(Wi, Wp, WT);

  gemm3bf<<<dim3(D_DIM / 64, MROWS / 64, 2), 256, 0, stream>>>(
      Xh, Xm, Xl, WT, I);

  prep_kernel<<<T_LEN + 1024, 256, 0, stream>>>(tab, pal, palT);

  rope_norm_kernel<<<MROWS, 256, 0, stream>>>(I, P, tab, nIb, nPb, Ih, Ph);

  screen_bf16<<<dim3(272, 1, 2), 256, 0, stream>>>(Ih, Ph, Ssc);

  topk_screen<<<dim3(T_LEN / 4, BATCH), 256, 0, stream>>>(Ssc, cand);

  rescore_kernel<<<MROWS, 256, 0, stream>>>(I, P, cand, idx);

  woconvT<<<dim3(D_DIM / 64, D_DIM / 64), 256, 0, stream>>>(Wo, WohT, WolT);

  relmlp_kernel<<<MROWS / 4, 256, 0, stream>>>(Ih, Ph, nIb, nPb, idx,
                                               W1, b1, W2, b2, Wc, bc, Wm, bm,
                                               palT, Vh, Vl);

  gemmbf<<<dim3(D_DIM / 128, MROWS / 64), 256, 0, stream>>>(
      Vh, Vl, WohT, WolT, out, D_DIM, D_DIM);
}

// Round 18
// 482.697 us; speedup vs baseline: 1.2873x; 1.2873x over previous
//
#include <hip/hip_runtime.h>
#include <math.h>

// Problem constants (fixed by the reference)
#define BATCH 2
#define T_LEN 2048
#define D_DIM 1024
#define KSEL  15
#define HIDN  64
#define NCAND 20

typedef short  bf16x8 __attribute__((ext_vector_type(8)));
typedef float  f32x4v __attribute__((ext_vector_type(4)));

__device__ __forceinline__ float geluf(float x) {
  return 0.5f * x * (1.0f + erff(x * 0.70710678118654752440f));
}

__device__ __forceinline__ unsigned short f32_to_bf16_rne(float x) {
  unsigned u = __builtin_bit_cast(unsigned, x);
  unsigned lsb = (u >> 16) & 1u;
  u += 0x7fffu + lsb;
  return (unsigned short)(u >> 16);
}
__device__ __forceinline__ float bf16_to_f32(unsigned short h) {
  unsigned u = ((unsigned)h) << 16;
  return __builtin_bit_cast(float, u);
}

// ---------------------------------------------------------------------------
// x -> 3 bf16 planes (h, m, l): x ~= h + m + l to ~2^-27 relative.
// ---------------------------------------------------------------------------
__global__ void __launch_bounds__(256) xsplit3(const float* __restrict__ X,
                                               unsigned short* __restrict__ H,
                                               unsigned short* __restrict__ M,
                                               unsigned short* __restrict__ L)
{
  const size_t i = ((size_t)blockIdx.x * 256 + threadIdx.x) * 4;
  float4 v = *(const float4*)(X + i);
  ushort4 h, m, l;
  float r;
  h.x = f32_to_bf16_rne(v.x); r = v.x - bf16_to_f32(h.x);
  m.x = f32_to_bf16_rne(r);   l.x = f32_to_bf16_rne(r - bf16_to_f32(m.x));
  h.y = f32_to_bf16_rne(v.y); r = v.y - bf16_to_f32(h.y);
  m.y = f32_to_bf16_rne(r);   l.y = f32_to_bf16_rne(r - bf16_to_f32(m.y));
  h.z = f32_to_bf16_rne(v.z); r = v.z - bf16_to_f32(h.z);
  m.z = f32_to_bf16_rne(r);   l.z = f32_to_bf16_rne(r - bf16_to_f32(m.z));
  h.w = f32_to_bf16_rne(v.w); r = v.w - bf16_to_f32(h.w);
  m.w = f32_to_bf16_rne(r);   l.w = f32_to_bf16_rne(r - bf16_to_f32(m.w));
  *(ushort4*)(H + i) = h;
  *(ushort4*)(M + i) = m;
  *(ushort4*)(L + i) = l;
}

// ---------------------------------------------------------------------------
// W (K x N, z picks Wi/Wp) -> transposed (N x K) 3 bf16 planes.
// ---------------------------------------------------------------------------
__global__ void __launch_bounds__(256) wsplit3T(const float* __restrict__ Wi,
                                                const float* __restrict__ Wp,
                                                unsigned short* __restrict__ WT)
{
  __shared__ float tile[64][65];
  const int k0 = blockIdx.y << 6, n0 = blockIdx.x << 6;
  const int z = blockIdx.z;
  const float* W = z ? Wp : Wi;
  unsigned short* H = WT + (size_t)z * 3 * 1024 * 1024;
  unsigned short* M = H + (size_t)1024 * 1024;
  unsigned short* L = M + (size_t)1024 * 1024;
  const int tid = threadIdx.x;
  for (int idx = tid; idx < 4096; idx += 256) {
    int r = idx >> 6, c = idx & 63;
    tile[r][c] = W[(size_t)(k0 + r) * D_DIM + n0 + c];
  }
  __syncthreads();
  for (int idx = tid; idx < 4096; idx += 256) {
    int n = idx >> 6, k = idx & 63;
    float v = tile[k][n];
    unsigned short h = f32_to_bf16_rne(v);
    float r1 = v - bf16_to_f32(h);
    unsigned short m = f32_to_bf16_rne(r1);
    unsigned short l = f32_to_bf16_rne(r1 - bf16_to_f32(m));
    size_t o = (size_t)(n0 + n) * D_DIM + k0 + k;
    H[o] = h; M[o] = m; L[o] = l;
  }
}

// ---------------------------------------------------------------------------
// 3-plane split-bf16 MFMA GEMM for I = x@Wi (z=0), P = x@Wp (z=1).
// (r14/r15, unchanged.)
// ---------------------------------------------------------------------------
__global__ void __launch_bounds__(256) gemm3bf(
    const unsigned short* __restrict__ Xh, const unsigned short* __restrict__ Xm,
    const unsigned short* __restrict__ Xl, const unsigned short* __restrict__ WT,
    float* __restrict__ C)
{
  const int m0 = blockIdx.y << 6, n0 = blockIdx.x << 6;
  const int z = blockIdx.z;
  const unsigned short* BhT = WT + (size_t)z * 3 * 1024 * 1024;
  const unsigned short* BmT = BhT + (size_t)1024 * 1024;
  const unsigned short* BlT = BmT + (size_t)1024 * 1024;
  C += (size_t)z * 4096 * 1024;
  const int N = D_DIM, K = D_DIM;

  const int tid = threadIdx.x;
  const int w = tid >> 6, lane = tid & 63;
  const int kg = lane >> 4, lm = lane & 15;
  const int am0 = (w & 1) << 5;
  const int bn0 = (w >> 1) << 5;

  __shared__ unsigned short Ah[2][64][40], Am[2][64][40], Al[2][64][40];
  __shared__ unsigned short Bh[2][64][40], Bm[2][64][40], Bl[2][64][40];

  bf16x8 ones;
#pragma unroll
  for (int e = 0; e < 8; ++e) ones[e] = (short)0x3F80;

  for (int idx = tid; idx < 2048; idx += 256) {
    Ah[0][idx >> 5][idx & 31] = f32_to_bf16_rne((float)(idx >> 5));
    Bh[0][idx >> 5][idx & 31] = f32_to_bf16_rne((float)(idx >> 5));
  }
  __syncthreads();
  int mr[4], nc[4];
  {
    bf16x8 pa = *(const bf16x8*)&Ah[0][am0 + lm][kg << 3];
    bf16x8 pb = *(const bf16x8*)&Bh[0][bn0 + lm][kg << 3];
    f32x4v d1 = {0.f, 0.f, 0.f, 0.f}, d2 = {0.f, 0.f, 0.f, 0.f};
    d1 = __builtin_amdgcn_mfma_f32_16x16x32_bf16(pa, ones, d1, 0, 0, 0);
    d2 = __builtin_amdgcn_mfma_f32_16x16x32_bf16(ones, pb, d2, 0, 0, 0);
#pragma unroll
    for (int e = 0; e < 4; ++e) {
      mr[e] = ((int)d1[e]) >> 5;
      nc[e] = ((int)d2[e]) >> 5;
    }
  }
  __syncthreads();

  f32x4v ch[2][2], cm[2][2], cl[2][2];
#pragma unroll
  for (int i = 0; i < 2; ++i)
#pragma unroll
    for (int j = 0; j < 2; ++j) {
      ch[i][j] = (f32x4v){0.f, 0.f, 0.f, 0.f};
      cm[i][j] = (f32x4v){0.f, 0.f, 0.f, 0.f};
      cl[i][j] = (f32x4v){0.f, 0.f, 0.f, 0.f};
    }

  const int ar = tid >> 2, ak8 = (tid & 3) << 3;

  bf16x8 rah, ram, ral, rbh, rbm, rbl;

  {
    size_t ao = (size_t)(m0 + ar) * K + ak8;
    size_t bo = (size_t)(n0 + ar) * K + ak8;
    rah = *(const bf16x8*)(Xh + ao); ram = *(const bf16x8*)(Xm + ao);
    ral = *(const bf16x8*)(Xl + ao);
    rbh = *(const bf16x8*)(BhT + bo); rbm = *(const bf16x8*)(BmT + bo);
    rbl = *(const bf16x8*)(BlT + bo);
  }
  *(bf16x8*)&Ah[0][ar][ak8] = rah;
  *(bf16x8*)&Am[0][ar][ak8] = ram;
  *(bf16x8*)&Al[0][ar][ak8] = ral;
  *(bf16x8*)&Bh[0][ar][ak8] = rbh;
  *(bf16x8*)&Bm[0][ar][ak8] = rbm;
  *(bf16x8*)&Bl[0][ar][ak8] = rbl;
  __syncthreads();

  int buf = 0;
  for (int k0 = 0; k0 < K; k0 += 32) {
    const bool more = (k0 + 32) < K;
    if (more) {
      const int kn = k0 + 32;
      size_t ao = (size_t)(m0 + ar) * K + kn + ak8;
      size_t bo = (size_t)(n0 + ar) * K + kn + ak8;
      rah = *(const bf16x8*)(Xh + ao); ram = *(const bf16x8*)(Xm + ao);
      ral = *(const bf16x8*)(Xl + ao);
      rbh = *(const bf16x8*)(BhT + bo); rbm = *(const bf16x8*)(BmT + bo);
      rbl = *(const bf16x8*)(BlT + bo);
    }
    {
      bf16x8 a_h[2], a_m[2], a_l[2], b_h[2], b_m[2], b_l[2];
#pragma unroll
      for (int i = 0; i < 2; ++i) {
        const int rrow = am0 + (i << 4) + lm;
        a_h[i] = *(const bf16x8*)&Ah[buf][rrow][kg << 3];
        a_m[i] = *(const bf16x8*)&Am[buf][rrow][kg << 3];
        a_l[i] = *(const bf16x8*)&Al[buf][rrow][kg << 3];
        const int nrow = bn0 + (i << 4) + lm;
        b_h[i] = *(const bf16x8*)&Bh[buf][nrow][kg << 3];
        b_m[i] = *(const bf16x8*)&Bm[buf][nrow][kg << 3];
        b_l[i] = *(const bf16x8*)&Bl[buf][nrow][kg << 3];
      }
#pragma unroll
      for (int i = 0; i < 2; ++i)
#pragma unroll
        for (int j = 0; j < 2; ++j) {
          ch[i][j] = __builtin_amdgcn_mfma_f32_16x16x32_bf16(a_h[i], b_h[j], ch[i][j], 0, 0, 0);
          cm[i][j] = __builtin_amdgcn_mfma_f32_16x16x32_bf16(a_h[i], b_m[j], cm[i][j], 0, 0, 0);
          cm[i][j] = __builtin_amdgcn_mfma_f32_16x16x32_bf16(a_m[i], b_h[j], cm[i][j], 0, 0, 0);
          cl[i][j] = __builtin_amdgcn_mfma_f32_16x16x32_bf16(a_h[i], b_l[j], cl[i][j], 0, 0, 0);
          cl[i][j] = __builtin_amdgcn_mfma_f32_16x16x32_bf16(a_m[i], b_m[j], cl[i][j], 0, 0, 0);
          cl[i][j] = __builtin_amdgcn_mfma_f32_16x16x32_bf16(a_l[i], b_h[j], cl[i][j], 0, 0, 0);
        }
    }
    if (more) {
      const int nb = buf ^ 1;
      *(bf16x8*)&Ah[nb][ar][ak8] = rah;
      *(bf16x8*)&Am[nb][ar][ak8] = ram;
      *(bf16x8*)&Al[nb][ar][ak8] = ral;
      *(bf16x8*)&Bh[nb][ar][ak8] = rbh;
      *(bf16x8*)&Bm[nb][ar][ak8] = rbm;
      *(bf16x8*)&Bl[nb][ar][ak8] = rbl;
    }
    __syncthreads();
    buf ^= 1;
  }

#pragma unroll
  for (int i = 0; i < 2; ++i)
#pragma unroll
    for (int j = 0; j < 2; ++j)
#pragma unroll
      for (int e = 0; e < 4; ++e) {
        const int rrow = m0 + mr[e] + (i << 4);
        const int ccol = n0 + nc[e] + (j << 4);
        float v = (ch[i][j][e] + cm[i][j][e]) + cl[i][j][e];
        C[(size_t)rrow * N + ccol] = v;
      }
}

// ---------------------------------------------------------------------------
// PREP (fused): trig table (EXACT reference f32 bits — selection-critical)
// + palette transpose.
// ---------------------------------------------------------------------------
__global__ void __launch_bounds__(256) prep_kernel(float2* __restrict__ tab,
                                                   const float* __restrict__ pal,
                                                   float* __restrict__ palT)
{
  const int b = blockIdx.x;
  if (b < T_LEN) {
    const int t = b;
    for (int j = threadIdx.x; j < 512; j += 256) {
      double e = (double)j * (1.0 / 512.0);
      float pf = (float)pow(10000.0, e);
      float invf = 1.0f / pf;
      float angf = (float)t * invf;
      double s64, c64;
      sincos((double)angf, &s64, &c64);
      tab[(size_t)t * 512 + j] = make_float2((float)c64, (float)s64);
    }
  } else {
    const int bb = b - T_LEN;
    const int c = bb & 255, dg = bb >> 8;
    const int d = dg * 256 + threadIdx.x;
    palT[(size_t)c * D_DIM + d] = pal[(size_t)d * 256 + c];
  }
}

// ---------------------------------------------------------------------------
// RoPE in place + row L2 norms + bf16 hi planes Ih/Ph (fused emit).
// f32 rotation math unchanged — selection-critical.
// ---------------------------------------------------------------------------
__global__ void __launch_bounds__(256) rope_norm_kernel(
    float* __restrict__ bI, float* __restrict__ bP,
    const float2* __restrict__ tab,
    float* __restrict__ nI, float* __restrict__ nP,
    unsigned short* __restrict__ Ih, unsigned short* __restrict__ Ph)
{
  const int row = blockIdx.x;
  const int t = row & (T_LEN - 1);
  const int tid = threadIdx.x;
  __shared__ double redI[4], redP[4];
  double ssI = 0.0, ssP = 0.0;
  const size_t off = (size_t)row * D_DIM;
  for (int j = tid; j < 512; j += 256) {
    float2 cs = tab[(size_t)t * 512 + j];
    float c = cs.x, s = cs.y;

    float a1 = bI[off + j], a2 = bI[off + 512 + j];
    float o1 = __fsub_rn(__fmul_rn(a1, c), __fmul_rn(a2, s));
    float o2 = __fadd_rn(__fmul_rn(a1, s), __fmul_rn(a2, c));
    bI[off + j] = o1; bI[off + 512 + j] = o2;
    Ih[off + j] = f32_to_bf16_rne(o1); Ih[off + 512 + j] = f32_to_bf16_rne(o2);
    ssI += (double)o1 * o1 + (double)o2 * o2;

    float p1 = bP[off + j], p2 = bP[off + 512 + j];
    float q1 = __fsub_rn(__fmul_rn(p1, c), __fmul_rn(p2, s));
    float q2 = __fadd_rn(__fmul_rn(p1, s), __fmul_rn(p2, c));
    bP[off + j] = q1; bP[off + 512 + j] = q2;
    Ph[off + j] = f32_to_bf16_rne(q1); Ph[off + 512 + j] = f32_to_bf16_rne(q2);
    ssP += (double)q1 * q1 + (double)q2 * q2;
  }
#pragma unroll
  for (int o = 32; o >= 1; o >>= 1) { ssI += __shfl_xor(ssI, o); ssP += __shfl_xor(ssP, o); }
  if ((tid & 63) == 0) { redI[tid >> 6] = ssI; redP[tid >> 6] = ssP; }
  __syncthreads();
  if (tid == 0) {
    nI[row] = fmaxf((float)sqrt(redI[0] + redI[1] + redI[2] + redI[3]), 1e-12f);
    nP[row] = fmaxf((float)sqrt(redP[0] + redP[1] + redP[2] + redP[3]), 1e-12f);
  }
}

// ---------------------------------------------------------------------------
// bf16 SCREEN for S (candidates only; exact rescore follows). (unchanged.)
// ---------------------------------------------------------------------------
__global__ void __launch_bounds__(256) screen_bf16(
    const unsigned short* __restrict__ Ih, const unsigned short* __restrict__ Ph,
    unsigned short* __restrict__ Ssc)
{
  int rem = blockIdx.x, bi = 0;
  while (rem >= (bi >> 1) + 1) { rem -= (bi >> 1) + 1; ++bi; }
  const int m0 = bi << 6, n0 = rem << 7;
  const int z = blockIdx.z;
  const unsigned short* A = Ih + (size_t)z * T_LEN * D_DIM;
  const unsigned short* B = Ph + (size_t)z * T_LEN * D_DIM;
  unsigned short* C = Ssc + (size_t)z * T_LEN * T_LEN;
  const int N = T_LEN, K = D_DIM;

  const int tid = threadIdx.x;
  const int w = tid >> 6, lane = tid & 63;
  const int kg = lane >> 4, lm = lane & 15;
  const int am0 = (w & 1) << 5;
  const int bn0 = (w >> 1) << 6;

  __shared__ unsigned short As_h[2][64][40];
  __shared__ unsigned short Bs_h[2][128][40];

  bf16x8 ones;
#pragma unroll
  for (int e = 0; e < 8; ++e) ones[e] = (short)0x3F80;

  for (int idx = tid; idx < 2048; idx += 256)
    As_h[0][idx >> 5][idx & 31] = f32_to_bf16_rne((float)(idx >> 5));
  for (int idx = tid; idx < 4096; idx += 256)
    Bs_h[0][idx >> 5][idx & 31] = f32_to_bf16_rne((float)(idx >> 5));
  __syncthreads();
  int mr[4], nc[4];
  {
    bf16x8 pa = *(const bf16x8*)&As_h[0][am0 + lm][kg << 3];
    bf16x8 pb = *(const bf16x8*)&Bs_h[0][bn0 + lm][kg << 3];
    f32x4v d1 = {0.f, 0.f, 0.f, 0.f}, d2 = {0.f, 0.f, 0.f, 0.f};
    d1 = __builtin_amdgcn_mfma_f32_16x16x32_bf16(pa, ones, d1, 0, 0, 0);
    d2 = __builtin_amdgcn_mfma_f32_16x16x32_bf16(ones, pb, d2, 0, 0, 0);
#pragma unroll
    for (int e = 0; e < 4; ++e) {
      mr[e] = ((int)d1[e]) >> 5;
      nc[e] = ((int)d2[e]) >> 5;
    }
  }
  __syncthreads();

  f32x4v c00 = {0,0,0,0}, c01 = {0,0,0,0}, c02 = {0,0,0,0}, c03 = {0,0,0,0};
  f32x4v c10 = {0,0,0,0}, c11 = {0,0,0,0}, c12 = {0,0,0,0}, c13 = {0,0,0,0};

  const int ar  = tid >> 2, ak8 = (tid & 3) << 3;
  const int bna = tid >> 2, bnb = 64 + (tid >> 2), bk8 = (tid & 3) << 3;

  bf16x8 ra, rb0, rb1;

  ra  = *(const bf16x8*)(A + (size_t)(m0 + ar) * K + ak8);
  rb0 = *(const bf16x8*)(B + (size_t)(n0 + bna) * K + bk8);
  rb1 = *(const bf16x8*)(B + (size_t)(n0 + bnb) * K + bk8);
  *(bf16x8*)&As_h[0][ar][ak8]  = ra;
  *(bf16x8*)&Bs_h[0][bna][bk8] = rb0;
  *(bf16x8*)&Bs_h[0][bnb][bk8] = rb1;
  __syncthreads();

  int buf = 0;
  for (int k0 = 0; k0 < K; k0 += 32) {
    const bool more = (k0 + 32) < K;
    if (more) {
      const int kn = k0 + 32;
      ra  = *(const bf16x8*)(A + (size_t)(m0 + ar) * K + kn + ak8);
      rb0 = *(const bf16x8*)(B + (size_t)(n0 + bna) * K + kn + bk8);
      rb1 = *(const bf16x8*)(B + (size_t)(n0 + bnb) * K + kn + bk8);
    }
    {
      bf16x8 a0 = *(const bf16x8*)&As_h[buf][am0 + lm][kg << 3];
      bf16x8 a1 = *(const bf16x8*)&As_h[buf][am0 + 16 + lm][kg << 3];
      bf16x8 b0 = *(const bf16x8*)&Bs_h[buf][bn0 + lm][kg << 3];
      bf16x8 b1 = *(const bf16x8*)&Bs_h[buf][bn0 + 16 + lm][kg << 3];
      bf16x8 b2 = *(const bf16x8*)&Bs_h[buf][bn0 + 32 + lm][kg << 3];
      bf16x8 b3 = *(const bf16x8*)&Bs_h[buf][bn0 + 48 + lm][kg << 3];
      c00 = __builtin_amdgcn_mfma_f32_16x16x32_bf16(a0, b0, c00, 0, 0, 0);
      c01 = __builtin_amdgcn_mfma_f32_16x16x32_bf16(a0, b1, c01, 0, 0, 0);
      c02 = __builtin_amdgcn_mfma_f32_16x16x32_bf16(a0, b2, c02, 0, 0, 0);
      c03 = __builtin_amdgcn_mfma_f32_16x16x32_bf16(a0, b3, c03, 0, 0, 0);
      c10 = __builtin_amdgcn_mfma_f32_16x16x32_bf16(a1, b0, c10, 0, 0, 0);
      c11 = __builtin_amdgcn_mfma_f32_16x16x32_bf16(a1, b1, c11, 0, 0, 0);
      c12 = __builtin_amdgcn_mfma_f32_16x16x32_bf16(a1, b2, c12, 0, 0, 0);
      c13 = __builtin_amdgcn_mfma_f32_16x16x32_bf16(a1, b3, c13, 0, 0, 0);
    }
    if (more) {
      const int nb = buf ^ 1;
      *(bf16x8*)&As_h[nb][ar][ak8]  = ra;
      *(bf16x8*)&Bs_h[nb][bna][bk8] = rb0;
      *(bf16x8*)&Bs_h[nb][bnb][bk8] = rb1;
    }
    __syncthreads();
    buf ^= 1;
  }

#pragma unroll
  for (int e = 0; e < 4; ++e) {
    const size_t r0 = (size_t)(m0 + mr[e]) * N;
    const size_t r1 = r0 + (size_t)16 * N;
    const int c = n0 + nc[e];
    C[r0 + c +  0] = f32_to_bf16_rne(c00[e]);
    C[r0 + c + 16] = f32_to_bf16_rne(c01[e]);
    C[r0 + c + 32] = f32_to_bf16_rne(c02[e]);
    C[r0 + c + 48] = f32_to_bf16_rne(c03[e]);
    C[r1 + c +  0] = f32_to_bf16_rne(c10[e]);
    C[r1 + c + 16] = f32_to_bf16_rne(c11[e]);
    C[r1 + c + 32] = f32_to_bf16_rne(c12[e]);
    C[r1 + c + 48] = f32_to_bf16_rne(c13[e]);
  }
}

// ---------------------------------------------------------------------------
// Top-NCAND screen candidates per causal row (bf16 S). -1 = invalid.
// ---------------------------------------------------------------------------
__global__ void __launch_bounds__(256) topk_screen(const unsigned short* __restrict__ Ssc,
                                                   int* __restrict__ cand)
{
  const int b = blockIdx.y;
  const unsigned short* S = Ssc + (size_t)b * T_LEN * T_LEN;
  const int wave = threadIdx.x >> 6, lane = threadIdx.x & 63;
  const int t = blockIdx.x * 4 + wave;
  const unsigned short* rowp = S + (size_t)t * T_LEN;
  float v[32];
#pragma unroll
  for (int i = 0; i < 32; ++i) {
    int s = lane + (i << 6);
    v[i] = (s <= t) ? bf16_to_f32(rowp[s]) : -INFINITY;
  }
  float pv = INFINITY; int pidx = -1;
  int* outp = cand + ((size_t)b * T_LEN + t) * NCAND;
  for (int k = 0; k < NCAND; ++k) {
    float bv = -INFINITY; int bi = 0x7fffffff;
#pragma unroll
    for (int i = 0; i < 32; ++i) {
      int s = lane + (i << 6);
      float vv = v[i];
      bool elig = (vv < pv) || (vv == pv && s > pidx);
      if (elig && vv > bv) { bv = vv; bi = s; }
    }
#pragma unroll
    for (int o = 32; o >= 1; o >>= 1) {
      float ov = __shfl_xor(bv, o);
      int oi = __shfl_xor(bi, o);
      if (ov > bv || (ov == bv && oi < bi)) { bv = ov; bi = oi; }
    }
    pv = bv; pidx = bi;
    if (lane == 0) outp[k] = (bi == 0x7fffffff || bv == -INFINITY) ? -1 : bi;
  }
}

// ---------------------------------------------------------------------------
// Exact rescore: f64 dot of I_t with each candidate P row (f32 arrays),
// rounded to f32 after the 2^-5 scale, tie -> lower index, top-15 -> idx.
// ---------------------------------------------------------------------------
__global__ void __launch_bounds__(256) rescore_kernel(
    const float* __restrict__ I, const float* __restrict__ P,
    const int* __restrict__ cand, int* __restrict__ idx)
{
  const int row = blockIdx.x;
  const int base = row & ~(T_LEN - 1);
  const int tid = threadIdx.x;
  const int w = tid >> 6, lane = tid & 63;

  __shared__ float valS[NCAND];
  __shared__ int   sidxS[NCAND];
  __shared__ int   candS[NCAND];

  if (tid < NCAND) candS[tid] = cand[(size_t)row * NCAND + tid];
  __syncthreads();

  double iv[16];
  const float* irow = I + (size_t)row * D_DIM;
#pragma unroll
  for (int j = 0; j < 16; ++j) iv[j] = (double)irow[lane + (j << 6)];

  for (int c = w; c < NCAND; c += 4) {
    int s = candS[c];
    double acc = 0.0;
    if (s >= 0) {
      const float* prow = P + ((size_t)base + s) * D_DIM;
#pragma unroll
      for (int j = 0; j < 16; ++j)
        acc = fma(iv[j], (double)prow[lane + (j << 6)], acc);
    }
#pragma unroll
    for (int o = 32; o >= 1; o >>= 1) acc += __shfl_xor(acc, o);
    if (lane == 0) {
      valS[c] = (s >= 0) ? (float)(acc * 0.03125) : -INFINITY;
      sidxS[c] = s;
    }
  }
  __syncthreads();
  if (tid == 0) {
    bool taken[NCAND];
#pragma unroll
    for (int c = 0; c < NCAND; ++c) taken[c] = false;
    int* outp = idx + (size_t)row * 16;
    for (int k = 0; k < KSEL; ++k) {
      float best = -INFINITY; int bidx = 0x7fffffff; int bc = -1;
      for (int c = 0; c < NCAND; ++c) {
        if (taken[c] || sidxS[c] < 0) continue;
        float v = valS[c];
        if (v > best || (v == best && sidxS[c] < bidx)) { best = v; bidx = sidxS[c]; bc = c; }
      }
      if (bc >= 0) { taken[bc] = true; outp[k] = bidx; }
      else outp[k] = 0;
    }
  }
}

// ---------------------------------------------------------------------------
// Wo (K x N) -> transposed bf16 hi/lo planes (N x K). After rescore (P dead).
// ---------------------------------------------------------------------------
__global__ void __launch_bounds__(256) woconvT(const float* __restrict__ Wo,
                                               unsigned short* __restrict__ HT,
                                               unsigned short* __restrict__ LT)
{
  __shared__ float tile[64][65];
  const int k0 = blockIdx.y << 6, n0 = blockIdx.x << 6;
  const int tid = threadIdx.x;
  for (int idx = tid; idx < 4096; idx += 256) {
    int r = idx >> 6, c = idx & 63;
    tile[r][c] = Wo[(size_t)(k0 + r) * D_DIM + n0 + c];
  }
  __syncthreads();
  for (int idx = tid; idx < 4096; idx += 256) {
    int n = idx >> 6, k = idx & 63;
    float v = tile[k][n];
    unsigned short h = f32_to_bf16_rne(v);
    HT[(size_t)(n0 + n) * D_DIM + k0 + k] = h;
    LT[(size_t)(n0 + n) * D_DIM + k0 + k] = f32_to_bf16_rne(v - bf16_to_f32(h));
  }
}

// ---------------------------------------------------------------------------
// Per-(b,t), WAVE-PER-ROW: gram via 4-accumulator MFMA chains + palette
// blend with SWAPPED LOOPS: j outer (runtime 60), d inner (16 persistent
// f32 accumulators per lane). Each j reads ONE palette row (L1-hot); 16
// independent loads+FMAs per j hide latency without the r17 VGPR blowup.
// Per-element j-order is ascending -> bit-identical to r16.
// ---------------------------------------------------------------------------
__global__ void __launch_bounds__(256) relmlp_kernel(
    const unsigned short* __restrict__ Ih, const unsigned short* __restrict__ Ph,
    const float* __restrict__ nI, const float* __restrict__ nP,
    const int* __restrict__ topk,
    const float* __restrict__ W1, const float* __restrict__ b1,
    const float* __restrict__ W2, const float* __restrict__ b2,
    const float* __restrict__ Wc, const float* __restrict__ bc,
    const float* __restrict__ Wm, const float* __restrict__ bm,
    const float* __restrict__ palT,
    unsigned short* __restrict__ Vh, unsigned short* __restrict__ Vl)
{
  const int wv   = threadIdx.x >> 6;          // wave id: row owner
  const int lane = threadIdx.x & 63;
  const int row  = (blockIdx.x << 2) + wv;
  const int t    = row & (T_LEN - 1);
  const int base = row & ~(T_LEN - 1);
  const int nk   = (t + 1 < KSEL) ? (t + 1) : KSEL;

  __shared__ int   sidxS[4][16];
  __shared__ float nrmS[4][16];
  __shared__ float gS[4][16][16];
  __shared__ float relS[4][KSEL][18];
  __shared__ float h1S[4][KSEL][HIDN];
  __shared__ float h2S[4][KSEL][HIDN];
  __shared__ float mixS[4][KSEL], wSS[4][KSEL], zxS[4][KSEL], zyS[4][KSEL];
  __shared__ float coefS[4][4 * KSEL];
  __shared__ int   cellS[4][4 * KSEL];

  if (lane < 16) {
    int s = t;
    if (lane >= 1) s = (lane <= nk) ? topk[(size_t)row * 16 + (lane - 1)] : 0;
    sidxS[wv][lane] = s;
    nrmS[wv][lane] = (lane == 0) ? nI[row] : nP[base + s];
  }
  __syncthreads();

  // ---- gram: direct-global MFMA fragments, 4 independent accumulators ----
  const int lm = lane & 15, kg = lane >> 4;
  {
    const unsigned short* src = (lm == 0)
        ? (Ih + (size_t)row * D_DIM)
        : (Ph + ((size_t)base + sidxS[wv][lm]) * D_DIM);
    f32x4v acc0 = {0.f, 0.f, 0.f, 0.f}, acc1 = {0.f, 0.f, 0.f, 0.f};
    f32x4v acc2 = {0.f, 0.f, 0.f, 0.f}, acc3 = {0.f, 0.f, 0.f, 0.f};
#pragma unroll
    for (int ks = 0; ks < 32; ks += 4) {
      bf16x8 a0, a1, a2, a3;
      if (lm <= nk) {
        a0 = *(const bf16x8*)(src + ((ks + 0) << 5) + (kg << 3));
        a1 = *(const bf16x8*)(src + ((ks + 1) << 5) + (kg << 3));
        a2 = *(const bf16x8*)(src + ((ks + 2) << 5) + (kg << 3));
        a3 = *(const bf16x8*)(src + ((ks + 3) << 5) + (kg << 3));
      } else {
        bf16x8 zz = {0, 0, 0, 0, 0, 0, 0, 0};
        a0 = zz; a1 = zz; a2 = zz; a3 = zz;
      }
      acc0 = __builtin_amdgcn_mfma_f32_16x16x32_bf16(a0, a0, acc0, 0, 0, 0);
      acc1 = __builtin_amdgcn_mfma_f32_16x16x32_bf16(a1, a1, acc1, 0, 0, 0);
      acc2 = __builtin_amdgcn_mfma_f32_16x16x32_bf16(a2, a2, acc2, 0, 0, 0);
      acc3 = __builtin_amdgcn_mfma_f32_16x16x32_bf16(a3, a3, acc3, 0, 0, 0);
    }
    f32x4v acc;
#pragma unroll
    for (int e = 0; e < 4; ++e)
      acc[e] = (acc0[e] + acc1[e]) + (acc2[e] + acc3[e]);

    bf16x8 pa, ones;
    unsigned short lmb = f32_to_bf16_rne((float)lm);
#pragma unroll
    for (int e = 0; e < 8; ++e) { pa[e] = (short)lmb; ones[e] = (short)0x3F80; }
    f32x4v d1 = {0.f, 0.f, 0.f, 0.f}, d2 = {0.f, 0.f, 0.f, 0.f};
    d1 = __builtin_amdgcn_mfma_f32_16x16x32_bf16(pa, ones, d1, 0, 0, 0);
    d2 = __builtin_amdgcn_mfma_f32_16x16x32_bf16(ones, pa, d2, 0, 0, 0);
#pragma unroll
    for (int e = 0; e < 4; ++e) {
      int pi2 = ((int)d1[e]) >> 5;
      int pj2 = ((int)d2[e]) >> 5;
      float g = 0.f;
      if (pi2 <= nk && pj2 <= nk) {
        g = acc[e] / (nrmS[wv][pi2] * nrmS[wv][pj2]);
        g = fminf(fmaxf(g, -1.f), 1.f);
      }
      gS[wv][pi2][pj2] = g;
    }
  }
  __syncthreads();

  // ---- rel features ----
  for (int o = lane; o < KSEL * 17; o += 64) {
    int k = o / 17, f = o % 17;
    float v = 0.f;
    if (k < nk) {
      if (f < KSEL)        v = (f < nk) ? gS[wv][k + 1][f + 1] : 0.f;
      else if (f == KSEL)  v = gS[wv][0][k + 1];
      else                 v = (float)(t - sidxS[wv][k + 1]) * (1.0f / (float)T_LEN);
    }
    relS[wv][k][f] = v;
  }
  __syncthreads();

  // ---- MLP1: lane = output channel m ----
#pragma unroll
  for (int k = 0; k < KSEL; ++k) {
    float a = b1[lane];
#pragma unroll
    for (int f = 0; f < 17; ++f) a = fmaf(relS[wv][k][f], W1[f * HIDN + lane], a);
    h1S[wv][k][lane] = geluf(a);
  }
  __syncthreads();

  // ---- MLP2 ----
#pragma unroll
  for (int k = 0; k < KSEL; ++k) {
    float a = b2[lane];
#pragma unroll 8
    for (int n = 0; n < HIDN; ++n) a = fmaf(h1S[wv][k][n], W2[n * HIDN + lane], a);
    h2S[wv][k][lane] = geluf(a);
  }
  __syncthreads();

  // ---- heads ----
  if (lane < KSEL) {
    float a0 = 0.f, a1 = 0.f, am = 0.f;
#pragma unroll 8
    for (int n = 0; n < HIDN; ++n) {
      float h = h2S[wv][lane][n];
      a0 = fmaf(h, Wc[n * 2 + 0], a0);
      a1 = fmaf(h, Wc[n * 2 + 1], a1);
      am = fmaf(h, Wm[n], am);
    }
    zxS[wv][lane] = tanhf(a0 + bc[0]);
    zyS[wv][lane] = tanhf(a1 + bc[1]);
    mixS[wv][lane] = am + bm[0];
  }
  __syncthreads();

  // ---- softmax (lane 0 of each wave) ----
  if (lane == 0) {
    float mx = -INFINITY;
    for (int k = 0; k < nk; ++k) mx = fmaxf(mx, mixS[wv][k]);
    float ssum = 0.f;
    for (int k = 0; k < nk; ++k) { float e = expf(mixS[wv][k] - mx); wSS[wv][k] = e; ssum += e; }
    float inv = 1.f / ssum;
    for (int k = 0; k < nk; ++k) wSS[wv][k] *= inv;
  }
  __syncthreads();

  // ---- bilinear coefficients ----
  if (lane < KSEL) {
    int k = lane;
    if (k < nk) {
      float w = wSS[wv][k];
      float fx = fminf(fmaxf((zxS[wv][k] + 1.f) * 0.5f * 15.f, 0.f), 15.f);
      float fy = fminf(fmaxf((zyS[wv][k] + 1.f) * 0.5f * 15.f, 0.f), 15.f);
      int x0 = (int)floorf(fx); int x1i = (x0 + 1 < 15) ? x0 + 1 : 15;
      int y0 = (int)floorf(fy); int y1i = (y0 + 1 < 15) ? y0 + 1 : 15;
      float wx = fx - (float)x0, wy = fy - (float)y0;
      cellS[wv][k * 4 + 0] = y0 * 16 + x0;   coefS[wv][k * 4 + 0] = w * (1.f - wy) * (1.f - wx);
      cellS[wv][k * 4 + 1] = y0 * 16 + x1i;  coefS[wv][k * 4 + 1] = w * (1.f - wy) * wx;
      cellS[wv][k * 4 + 2] = y1i * 16 + x0;  coefS[wv][k * 4 + 2] = w * wy * (1.f - wx);
      cellS[wv][k * 4 + 3] = y1i * 16 + x1i; coefS[wv][k * 4 + 3] = w * wy * wx;
    } else {
      cellS[wv][k * 4 + 0] = cellS[wv][k * 4 + 1] = cellS[wv][k * 4 + 2] = cellS[wv][k * 4 + 3] = 0;
      coefS[wv][k * 4 + 0] = coefS[wv][k * 4 + 1] = coefS[wv][k * 4 + 2] = coefS[wv][k * 4 + 3] = 0.f;
    }
  }
  __syncthreads();

  // ---- palette blend: j OUTER (runtime 60), d INNER (16 accumulators) ----
  {
    float av[16];
#pragma unroll
    for (int e = 0; e < 16; ++e) av[e] = 0.f;
    const int nj = 4 * nk;
    for (int j = 0; j < nj; ++j) {
      const float cf = coefS[wv][j];
      const float* prow = palT + (size_t)cellS[wv][j] * D_DIM + lane;
#pragma unroll
      for (int e = 0; e < 16; ++e)
        av[e] = fmaf(cf, prow[e << 6], av[e]);
    }
#pragma unroll
    for (int e = 0; e < 16; ++e) {
      const int d = lane + (e << 6);
      float a = av[e];
      unsigned short h = f32_to_bf16_rne(a);
      Vh[(size_t)row * D_DIM + d] = h;
      Vl[(size_t)row * D_DIM + d] = f32_to_bf16_rne(a - bf16_to_f32(h));
    }
  }
}

// ---------------------------------------------------------------------------
// Split-bf16 MFMA GEMM for out = V @ Wo. (r10, unchanged.)
// ---------------------------------------------------------------------------
__global__ void __launch_bounds__(256) gemmbf(
    const unsigned short* __restrict__ Ah, const unsigned short* __restrict__ Al,
    const unsigned short* __restrict__ BhT, const unsigned short* __restrict__ BlT,
    float* __restrict__ C, int N, int K)
{
  const int m0 = blockIdx.y << 6, n0 = blockIdx.x << 7;
  const int tid = threadIdx.x;
  const int w = tid >> 6, lane = tid & 63;
  const int kg = lane >> 4, lm = lane & 15;
  const int am0 = (w & 1) << 5;
  const int bn0 = (w >> 1) << 6;

  __shared__ unsigned short As_h[2][64][40],  As_l[2][64][40];
  __shared__ unsigned short Bs_h[2][128][40], Bs_l[2][128][40];

  bf16x8 ones;
#pragma unroll
  for (int e = 0; e < 8; ++e) ones[e] = (short)0x3F80;

  for (int idx = tid; idx < 2048; idx += 256)
    As_h[0][idx >> 5][idx & 31] = f32_to_bf16_rne((float)(idx >> 5));
  for (int idx = tid; idx < 4096; idx += 256)
    Bs_h[0][idx >> 5][idx & 31] = f32_to_bf16_rne((float)(idx >> 5));
  __syncthreads();
  int mr[4], nc[4];
  {
    bf16x8 pa = *(const bf16x8*)&As_h[0][am0 + lm][kg << 3];
    bf16x8 pb = *(const bf16x8*)&Bs_h[0][bn0 + lm][kg << 3];
    f32x4v d1 = {0.f, 0.f, 0.f, 0.f}, d2 = {0.f, 0.f, 0.f, 0.f};
    d1 = __builtin_amdgcn_mfma_f32_16x16x32_bf16(pa, ones, d1, 0, 0, 0);
    d2 = __builtin_amdgcn_mfma_f32_16x16x32_bf16(ones, pb, d2, 0, 0, 0);
#pragma unroll
    for (int e = 0; e < 4; ++e) {
      mr[e] = ((int)d1[e]) >> 5;
      nc[e] = ((int)d2[e]) >> 5;
    }
  }
  __syncthreads();

  f32x4v c00 = {0,0,0,0}, c01 = {0,0,0,0}, c02 = {0,0,0,0}, c03 = {0,0,0,0};
  f32x4v c10 = {0,0,0,0}, c11 = {0,0,0,0}, c12 = {0,0,0,0}, c13 = {0,0,0,0};

  const int ar  = tid >> 2, ak8 = (tid & 3) << 3;
  const int bna = tid >> 2, bnb = 64 + (tid >> 2), bk8 = (tid & 3) << 3;

  bf16x8 rah, ral, rbh0, rbl0, rbh1, rbl1;

  rah  = *(const bf16x8*)(Ah  + (size_t)(m0 + ar) * K + ak8);
  ral  = *(const bf16x8*)(Al  + (size_t)(m0 + ar) * K + ak8);
  rbh0 = *(const bf16x8*)(BhT + (size_t)(n0 + bna) * K + bk8);
  rbl0 = *(const bf16x8*)(BlT + (size_t)(n0 + bna) * K + bk8);
  rbh1 = *(const bf16x8*)(BhT + (size_t)(n0 + bnb) * K + bk8);
  rbl1 = *(const bf16x8*)(BlT + (size_t)(n0 + bnb) * K + bk8);
  *(bf16x8*)&As_h[0][ar][ak8]  = rah;
  *(bf16x8*)&As_l[0][ar][ak8]  = ral;
  *(bf16x8*)&Bs_h[0][bna][bk8] = rbh0;
  *(bf16x8*)&Bs_l[0][bna][bk8] = rbl0;
  *(bf16x8*)&Bs_h[0][bnb][bk8] = rbh1;
  *(bf16x8*)&Bs_l[0][bnb][bk8] = rbl1;
  __syncthreads();

  int buf = 0;
  for (int k0 = 0; k0 < K; k0 += 32) {
    const bool more = (k0 + 32) < K;
    if (more) {
      const int kn = k0 + 32;
      rah  = *(const bf16x8*)(Ah  + (size_t)(m0 + ar) * K + kn + ak8);
      ral  = *(const bf16x8*)(Al  + (size_t)(m0 + ar) * K + kn + ak8);
      rbh0 = *(const bf16x8*)(BhT + (size_t)(n0 + bna) * K + kn + bk8);
      rbl0 = *(const bf16x8*)(BlT + (size_t)(n0 + bna) * K + kn + bk8);
      rbh1 = *(const bf16x8*)(BhT + (size_t)(n0 + bnb) * K + kn + bk8);
      rbl1 = *(const bf16x8*)(BlT + (size_t)(n0 + bnb) * K + kn + bk8);
    }
    {
      bf16x8 ah0 = *(const bf16x8*)&As_h[buf][am0 + lm][kg << 3];
      bf16x8 ah1 = *(const bf16x8*)&As_h[buf][am0 + 16 + lm][kg << 3];
      bf16x8 al0 = *(const bf16x8*)&As_l[buf][am0 + lm][kg << 3];
      bf16x8 al1 = *(const bf16x8*)&As_l[buf][am0 + 16 + lm][kg << 3];
      bf16x8 bh0 = *(const bf16x8*)&Bs_h[buf][bn0 + lm][kg << 3];
      bf16x8 bh1 = *(const bf16x8*)&Bs_h[buf][bn0 + 16 + lm][kg << 3];
      bf16x8 bh2 = *(const bf16x8*)&Bs_h[buf][bn0 + 32 + lm][kg << 3];
      bf16x8 bh3 = *(const bf16x8*)&Bs_h[buf][bn0 + 48 + lm][kg << 3];
      bf16x8 bl0 = *(const bf16x8*)&Bs_l[buf][bn0 + lm][kg << 3];
      bf16x8 bl1 = *(const bf16x8*)&Bs_l[buf][bn0 + 16 + lm][kg << 3];
      bf16x8 bl2 = *(const bf16x8*)&Bs_l[buf][bn0 + 32 + lm][kg << 3];
      bf16x8 bl3 = *(const bf16x8*)&Bs_l[buf][bn0 + 48 + lm][kg << 3];

      c00 = __builtin_amdgcn_mfma_f32_16x16x32_bf16(ah0, bh0, c00, 0, 0, 0);
      c01 = __builtin_amdgcn_mfma_f32_16x16x32_bf16(ah0, bh1, c01, 0, 0, 0);
      c02 = __builtin_amdgcn_mfma_f32_16x16x32_bf16(ah0, bh2, c02, 0, 0, 0);
      c03 = __builtin_amdgcn_mfma_f32_16x16x32_bf16(ah0, bh3, c03, 0, 0, 0);
      c10 = __builtin_amdgcn_mfma_f32_16x16x32_bf16(ah1, bh0, c10, 0, 0, 0);
      c11 = __builtin_amdgcn_mfma_f32_16x16x32_bf16(ah1, bh1, c11, 0, 0, 0);
      c12 = __builtin_amdgcn_mfma_f32_16x16x32_bf16(ah1, bh2, c12, 0, 0, 0);
      c13 = __builtin_amdgcn_mfma_f32_16x16x32_bf16(ah1, bh3, c13, 0, 0, 0);

      c00 = __builtin_amdgcn_mfma_f32_16x16x32_bf16(ah0, bl0, c00, 0, 0, 0);
      c01 = __builtin_amdgcn_mfma_f32_16x16x32_bf16(ah0, bl1, c01, 0, 0, 0);
      c02 = __builtin_amdgcn_mfma_f32_16x16x32_bf16(ah0, bl2, c02, 0, 0, 0);
      c03 = __builtin_amdgcn_mfma_f32_16x16x32_bf16(ah0, bl3, c03, 0, 0, 0);
      c10 = __builtin_amdgcn_mfma_f32_16x16x32_bf16(ah1, bl0, c10, 0, 0, 0);
      c11 = __builtin_amdgcn_mfma_f32_16x16x32_bf16(ah1, bl1, c11, 0, 0, 0);
      c12 = __builtin_amdgcn_mfma_f32_16x16x32_bf16(ah1, bl2, c12, 0, 0, 0);
      c13 = __builtin_amdgcn_mfma_f32_16x16x32_bf16(ah1, bl3, c13, 0, 0, 0);

      c00 = __builtin_amdgcn_mfma_f32_16x16x32_bf16(al0, bh0, c00, 0, 0, 0);
      c01 = __builtin_amdgcn_mfma_f32_16x16x32_bf16(al0, bh1, c01, 0, 0, 0);
      c02 = __builtin_amdgcn_mfma_f32_16x16x32_bf16(al0, bh2, c02, 0, 0, 0);
      c03 = __builtin_amdgcn_mfma_f32_16x16x32_bf16(al0, bh3, c03, 0, 0, 0);
      c10 = __builtin_amdgcn_mfma_f32_16x16x32_bf16(al1, bh0, c10, 0, 0, 0);
      c11 = __builtin_amdgcn_mfma_f32_16x16x32_bf16(al1, bh1, c11, 0, 0, 0);
      c12 = __builtin_amdgcn_mfma_f32_16x16x32_bf16(al1, bh2, c12, 0, 0, 0);
      c13 = __builtin_amdgcn_mfma_f32_16x16x32_bf16(al1, bh3, c13, 0, 0, 0);
    }
    if (more) {
      const int nb = buf ^ 1;
      *(bf16x8*)&As_h[nb][ar][ak8]  = rah;
      *(bf16x8*)&As_l[nb][ar][ak8]  = ral;
      *(bf16x8*)&Bs_h[nb][bna][bk8] = rbh0;
      *(bf16x8*)&Bs_l[nb][bna][bk8] = rbl0;
      *(bf16x8*)&Bs_h[nb][bnb][bk8] = rbh1;
      *(bf16x8*)&Bs_l[nb][bnb][bk8] = rbl1;
    }
    __syncthreads();
    buf ^= 1;
  }

#pragma unroll
  for (int e = 0; e < 4; ++e) {
    const size_t r0 = (size_t)(m0 + mr[e]) * N;
    const size_t r1 = r0 + (size_t)16 * N;
    const int c = n0 + nc[e];
    C[r0 + c +  0] = c00[e];
    C[r0 + c + 16] = c01[e];
    C[r0 + c + 32] = c02[e];
    C[r0 + c + 48] = c03[e];
    C[r1 + c +  0] = c10[e];
    C[r1 + c + 16] = c11[e];
    C[r1 + c + 32] = c12[e];
    C[r1 + c + 48] = c13[e];
  }
}

// ---------------------------------------------------------------------------
// Host launcher. (r16 structure, unchanged.)
// ---------------------------------------------------------------------------
extern "C" void kernel_launch(void* const* d_in, const int* in_sizes, int n_in,
                              void* d_out, int out_size, void* d_ws, size_t ws_size,
                              hipStream_t stream)
{
  (void)in_sizes; (void)n_in; (void)out_size; (void)ws_size;
  const float* x   = (const float*)d_in[0];
  const float* Wi  = (const float*)d_in[1];
  const float* Wp  = (const float*)d_in[2];
  const float* pal = (const float*)d_in[3];
  const float* W1  = (const float*)d_in[4];
  const float* b1  = (const float*)d_in[5];
  const float* W2  = (const float*)d_in[6];
  const float* b2  = (const float*)d_in[7];
  const float* Wc  = (const float*)d_in[8];
  const float* bc  = (const float*)d_in[9];
  const float* Wm  = (const float*)d_in[10];
  const float* bm  = (const float*)d_in[11];
  const float* Wo  = (const float*)d_in[12];
  float* out = (float*)d_out;

  float* w = (float*)d_ws;
  float* palT = w;  w += (size_t)256 * D_DIM;
  float* I    = w;  w += (size_t)BATCH * T_LEN * D_DIM;
  float* P    = w;  w += (size_t)BATCH * T_LEN * D_DIM;
  float* Sb   = w;  w += (size_t)BATCH * T_LEN * T_LEN;
  float* nIb  = w;  w += (size_t)BATCH * T_LEN;
  float* nPb  = w;  w += (size_t)BATCH * T_LEN;
  int*   idx  = (int*)w;  w += (size_t)BATCH * T_LEN * 16;
  int*   cand = (int*)w;

  unsigned short* Xh = (unsigned short*)Sb;
  unsigned short* Xm = Xh + (size_t)4096 * 1024;
  unsigned short* Xl = Xm + (size_t)4096 * 1024;
  unsigned short* WT = (unsigned short*)d_out;

  float2* tab = (float2*)Sb;
  unsigned short* Ssc = (unsigned short*)Sb;
  unsigned short* Ih  = (unsigned short*)(Sb + (size_t)4 * 1024 * 1024);
  unsigned short* Ph  = Ih + (size_t)4 * 1024 * 1024;
  unsigned short* Vh  = (unsigned short*)Sb;
  unsigned short* Vl  = Vh + (size_t)4 * 1024 * 1024;
  unsigned short* WohT = (unsigned short*)P;
  unsigned short* WolT = WohT + (size_t)D_DIM * D_DIM;

  const int MROWS = BATCH * T_LEN;  // 4096

  xsplit3<<<(MROWS * D_DIM) / (256 * 4), 256, 0, stream>>>(x, Xh, Xm, Xl);
  wsplit3T<<<dim3(D_DIM / 64, D_DIM / 64, 2), 256, 0, stream>>>(Wi, Wp, WT);

  gemm3bf<<<dim3(D_DIM / 64, MROWS / 64, 2), 256, 0, stream>>>(
      Xh, Xm, Xl, WT, I);

  prep_kernel<<<T_LEN + 1024, 256, 0, stream>>>(tab, pal, palT);

  rope_norm_kernel<<<MROWS, 256, 0, stream>>>(I, P, tab, nIb, nPb, Ih, Ph);

  screen_bf16<<<dim3(272, 1, 2), 256, 0, stream>>>(Ih, Ph, Ssc);

  topk_screen<<<dim3(T_LEN / 4, BATCH), 256, 0, stream>>>(Ssc, cand);

  rescore_kernel<<<MROWS, 256, 0, stream>>>(I, P, cand, idx);

  woconvT<<<dim3(D_DIM / 64, D_DIM / 64), 256, 0, stream>>>(Wo, WohT, WolT);

  relmlp_kernel<<<MROWS / 4, 256, 0, stream>>>(Ih, Ph, nIb, nPb, idx,
                                               W1, b1, W2, b2, Wc, bc, Wm, bm,
                                               palT, Vh, Vl);

  gemmbf<<<dim3(D_DIM / 128, MROWS / 64), 256, 0, stream>>>(
      Vh, Vl, WohT, WolT, out, D_DIM, D_DIM);
}

// Round 19
// 480.353 us; speedup vs baseline: 1.2935x; 1.0049x over previous
//
#include <hip/hip_runtime.h>
#include <math.h>

// Problem constants (fixed by the reference)
#define BATCH 2
#define T_LEN 2048
#define D_DIM 1024
#define KSEL  15
#define HIDN  64
#define NCAND 20

typedef short  bf16x8 __attribute__((ext_vector_type(8)));
typedef float  f32x4v __attribute__((ext_vector_type(4)));

__device__ __forceinline__ float geluf(float x) {
  return 0.5f * x * (1.0f + erff(x * 0.70710678118654752440f));
}

__device__ __forceinline__ unsigned short f32_to_bf16_rne(float x) {
  unsigned u = __builtin_bit_cast(unsigned, x);
  unsigned lsb = (u >> 16) & 1u;
  u += 0x7fffu + lsb;
  return (unsigned short)(u >> 16);
}
__device__ __forceinline__ float bf16_to_f32(unsigned short h) {
  unsigned u = ((unsigned)h) << 16;
  return __builtin_bit_cast(float, u);
}

// ---------------------------------------------------------------------------
// x -> 3 bf16 planes (h, m, l): x ~= h + m + l to ~2^-27 relative.
// ---------------------------------------------------------------------------
__global__ void __launch_bounds__(256) xsplit3(const float* __restrict__ X,
                                               unsigned short* __restrict__ H,
                                               unsigned short* __restrict__ M,
                                               unsigned short* __restrict__ L)
{
  const size_t i = ((size_t)blockIdx.x * 256 + threadIdx.x) * 4;
  float4 v = *(const float4*)(X + i);
  ushort4 h, m, l;
  float r;
  h.x = f32_to_bf16_rne(v.x); r = v.x - bf16_to_f32(h.x);
  m.x = f32_to_bf16_rne(r);   l.x = f32_to_bf16_rne(r - bf16_to_f32(m.x));
  h.y = f32_to_bf16_rne(v.y); r = v.y - bf16_to_f32(h.y);
  m.y = f32_to_bf16_rne(r);   l.y = f32_to_bf16_rne(r - bf16_to_f32(m.y));
  h.z = f32_to_bf16_rne(v.z); r = v.z - bf16_to_f32(h.z);
  m.z = f32_to_bf16_rne(r);   l.z = f32_to_bf16_rne(r - bf16_to_f32(m.z));
  h.w = f32_to_bf16_rne(v.w); r = v.w - bf16_to_f32(h.w);
  m.w = f32_to_bf16_rne(r);   l.w = f32_to_bf16_rne(r - bf16_to_f32(m.w));
  *(ushort4*)(H + i) = h;
  *(ushort4*)(M + i) = m;
  *(ushort4*)(L + i) = l;
}

// ---------------------------------------------------------------------------
// W (K x N, z picks Wi/Wp) -> transposed (N x K) 3 bf16 planes.
// ---------------------------------------------------------------------------
__global__ void __launch_bounds__(256) wsplit3T(const float* __restrict__ Wi,
                                                const float* __restrict__ Wp,
                                                unsigned short* __restrict__ WT)
{
  __shared__ float tile[64][65];
  const int k0 = blockIdx.y << 6, n0 = blockIdx.x << 6;
  const int z = blockIdx.z;
  const float* W = z ? Wp : Wi;
  unsigned short* H = WT + (size_t)z * 3 * 1024 * 1024;
  unsigned short* M = H + (size_t)1024 * 1024;
  unsigned short* L = M + (size_t)1024 * 1024;
  const int tid = threadIdx.x;
  for (int idx = tid; idx < 4096; idx += 256) {
    int r = idx >> 6, c = idx & 63;
    tile[r][c] = W[(size_t)(k0 + r) * D_DIM + n0 + c];
  }
  __syncthreads();
  for (int idx = tid; idx < 4096; idx += 256) {
    int n = idx >> 6, k = idx & 63;
    float v = tile[k][n];
    unsigned short h = f32_to_bf16_rne(v);
    float r1 = v - bf16_to_f32(h);
    unsigned short m = f32_to_bf16_rne(r1);
    unsigned short l = f32_to_bf16_rne(r1 - bf16_to_f32(m));
    size_t o = (size_t)(n0 + n) * D_DIM + k0 + k;
    H[o] = h; M[o] = m; L[o] = l;
  }
}

// ---------------------------------------------------------------------------
// 3-plane split-bf16 MFMA GEMM for I = x@Wi (z=0), P = x@Wp (z=1).
// (r14/r15, unchanged.)
// ---------------------------------------------------------------------------
__global__ void __launch_bounds__(256) gemm3bf(
    const unsigned short* __restrict__ Xh, const unsigned short* __restrict__ Xm,
    const unsigned short* __restrict__ Xl, const unsigned short* __restrict__ WT,
    float* __restrict__ C)
{
  const int m0 = blockIdx.y << 6, n0 = blockIdx.x << 6;
  const int z = blockIdx.z;
  const unsigned short* BhT = WT + (size_t)z * 3 * 1024 * 1024;
  const unsigned short* BmT = BhT + (size_t)1024 * 1024;
  const unsigned short* BlT = BmT + (size_t)1024 * 1024;
  C += (size_t)z * 4096 * 1024;
  const int N = D_DIM, K = D_DIM;

  const int tid = threadIdx.x;
  const int w = tid >> 6, lane = tid & 63;
  const int kg = lane >> 4, lm = lane & 15;
  const int am0 = (w & 1) << 5;
  const int bn0 = (w >> 1) << 5;

  __shared__ unsigned short Ah[2][64][40], Am[2][64][40], Al[2][64][40];
  __shared__ unsigned short Bh[2][64][40], Bm[2][64][40], Bl[2][64][40];

  bf16x8 ones;
#pragma unroll
  for (int e = 0; e < 8; ++e) ones[e] = (short)0x3F80;

  for (int idx = tid; idx < 2048; idx += 256) {
    Ah[0][idx >> 5][idx & 31] = f32_to_bf16_rne((float)(idx >> 5));
    Bh[0][idx >> 5][idx & 31] = f32_to_bf16_rne((float)(idx >> 5));
  }
  __syncthreads();
  int mr[4], nc[4];
  {
    bf16x8 pa = *(const bf16x8*)&Ah[0][am0 + lm][kg << 3];
    bf16x8 pb = *(const bf16x8*)&Bh[0][bn0 + lm][kg << 3];
    f32x4v d1 = {0.f, 0.f, 0.f, 0.f}, d2 = {0.f, 0.f, 0.f, 0.f};
    d1 = __builtin_amdgcn_mfma_f32_16x16x32_bf16(pa, ones, d1, 0, 0, 0);
    d2 = __builtin_amdgcn_mfma_f32_16x16x32_bf16(ones, pb, d2, 0, 0, 0);
#pragma unroll
    for (int e = 0; e < 4; ++e) {
      mr[e] = ((int)d1[e]) >> 5;
      nc[e] = ((int)d2[e]) >> 5;
    }
  }
  __syncthreads();

  f32x4v ch[2][2], cm[2][2], cl[2][2];
#pragma unroll
  for (int i = 0; i < 2; ++i)
#pragma unroll
    for (int j = 0; j < 2; ++j) {
      ch[i][j] = (f32x4v){0.f, 0.f, 0.f, 0.f};
      cm[i][j] = (f32x4v){0.f, 0.f, 0.f, 0.f};
      cl[i][j] = (f32x4v){0.f, 0.f, 0.f, 0.f};
    }

  const int ar = tid >> 2, ak8 = (tid & 3) << 3;

  bf16x8 rah, ram, ral, rbh, rbm, rbl;

  {
    size_t ao = (size_t)(m0 + ar) * K + ak8;
    size_t bo = (size_t)(n0 + ar) * K + ak8;
    rah = *(const bf16x8*)(Xh + ao); ram = *(const bf16x8*)(Xm + ao);
    ral = *(const bf16x8*)(Xl + ao);
    rbh = *(const bf16x8*)(BhT + bo); rbm = *(const bf16x8*)(BmT + bo);
    rbl = *(const bf16x8*)(BlT + bo);
  }
  *(bf16x8*)&Ah[0][ar][ak8] = rah;
  *(bf16x8*)&Am[0][ar][ak8] = ram;
  *(bf16x8*)&Al[0][ar][ak8] = ral;
  *(bf16x8*)&Bh[0][ar][ak8] = rbh;
  *(bf16x8*)&Bm[0][ar][ak8] = rbm;
  *(bf16x8*)&Bl[0][ar][ak8] = rbl;
  __syncthreads();

  int buf = 0;
  for (int k0 = 0; k0 < K; k0 += 32) {
    const bool more = (k0 + 32) < K;
    if (more) {
      const int kn = k0 + 32;
      size_t ao = (size_t)(m0 + ar) * K + kn + ak8;
      size_t bo = (size_t)(n0 + ar) * K + kn + ak8;
      rah = *(const bf16x8*)(Xh + ao); ram = *(const bf16x8*)(Xm + ao);
      ral = *(const bf16x8*)(Xl + ao);
      rbh = *(const bf16x8*)(BhT + bo); rbm = *(const bf16x8*)(BmT + bo);
      rbl = *(const bf16x8*)(BlT + bo);
    }
    {
      bf16x8 a_h[2], a_m[2], a_l[2], b_h[2], b_m[2], b_l[2];
#pragma unroll
      for (int i = 0; i < 2; ++i) {
        const int rrow = am0 + (i << 4) + lm;
        a_h[i] = *(const bf16x8*)&Ah[buf][rrow][kg << 3];
        a_m[i] = *(const bf16x8*)&Am[buf][rrow][kg << 3];
        a_l[i] = *(const bf16x8*)&Al[buf][rrow][kg << 3];
        const int nrow = bn0 + (i << 4) + lm;
        b_h[i] = *(const bf16x8*)&Bh[buf][nrow][kg << 3];
        b_m[i] = *(const bf16x8*)&Bm[buf][nrow][kg << 3];
        b_l[i] = *(const bf16x8*)&Bl[buf][nrow][kg << 3];
      }
#pragma unroll
      for (int i = 0; i < 2; ++i)
#pragma unroll
        for (int j = 0; j < 2; ++j) {
          ch[i][j] = __builtin_amdgcn_mfma_f32_16x16x32_bf16(a_h[i], b_h[j], ch[i][j], 0, 0, 0);
          cm[i][j] = __builtin_amdgcn_mfma_f32_16x16x32_bf16(a_h[i], b_m[j], cm[i][j], 0, 0, 0);
          cm[i][j] = __builtin_amdgcn_mfma_f32_16x16x32_bf16(a_m[i], b_h[j], cm[i][j], 0, 0, 0);
          cl[i][j] = __builtin_amdgcn_mfma_f32_16x16x32_bf16(a_h[i], b_l[j], cl[i][j], 0, 0, 0);
          cl[i][j] = __builtin_amdgcn_mfma_f32_16x16x32_bf16(a_m[i], b_m[j], cl[i][j], 0, 0, 0);
          cl[i][j] = __builtin_amdgcn_mfma_f32_16x16x32_bf16(a_l[i], b_h[j], cl[i][j], 0, 0, 0);
        }
    }
    if (more) {
      const int nb = buf ^ 1;
      *(bf16x8*)&Ah[nb][ar][ak8] = rah;
      *(bf16x8*)&Am[nb][ar][ak8] = ram;
      *(bf16x8*)&Al[nb][ar][ak8] = ral;
      *(bf16x8*)&Bh[nb][ar][ak8] = rbh;
      *(bf16x8*)&Bm[nb][ar][ak8] = rbm;
      *(bf16x8*)&Bl[nb][ar][ak8] = rbl;
    }
    __syncthreads();
    buf ^= 1;
  }

#pragma unroll
  for (int i = 0; i < 2; ++i)
#pragma unroll
    for (int j = 0; j < 2; ++j)
#pragma unroll
      for (int e = 0; e < 4; ++e) {
        const int rrow = m0 + mr[e] + (i << 4);
        const int ccol = n0 + nc[e] + (j << 4);
        float v = (ch[i][j][e] + cm[i][j][e]) + cl[i][j][e];
        C[(size_t)rrow * N + ccol] = v;
      }
}

// ---------------------------------------------------------------------------
// PREP (fused): trig table (EXACT reference f32 bits — selection-critical)
// + palette transpose.
// ---------------------------------------------------------------------------
__global__ void __launch_bounds__(256) prep_kernel(float2* __restrict__ tab,
                                                   const float* __restrict__ pal,
                                                   float* __restrict__ palT)
{
  const int b = blockIdx.x;
  if (b < T_LEN) {
    const int t = b;
    for (int j = threadIdx.x; j < 512; j += 256) {
      double e = (double)j * (1.0 / 512.0);
      float pf = (float)pow(10000.0, e);
      float invf = 1.0f / pf;
      float angf = (float)t * invf;
      double s64, c64;
      sincos((double)angf, &s64, &c64);
      tab[(size_t)t * 512 + j] = make_float2((float)c64, (float)s64);
    }
  } else {
    const int bb = b - T_LEN;
    const int c = bb & 255, dg = bb >> 8;
    const int d = dg * 256 + threadIdx.x;
    palT[(size_t)c * D_DIM + d] = pal[(size_t)d * 256 + c];
  }
}

// ---------------------------------------------------------------------------
// RoPE in place + row L2 norms + bf16 hi planes Ih/Ph (fused emit).
// f32 rotation math unchanged — selection-critical.
// ---------------------------------------------------------------------------
__global__ void __launch_bounds__(256) rope_norm_kernel(
    float* __restrict__ bI, float* __restrict__ bP,
    const float2* __restrict__ tab,
    float* __restrict__ nI, float* __restrict__ nP,
    unsigned short* __restrict__ Ih, unsigned short* __restrict__ Ph)
{
  const int row = blockIdx.x;
  const int t = row & (T_LEN - 1);
  const int tid = threadIdx.x;
  __shared__ double redI[4], redP[4];
  double ssI = 0.0, ssP = 0.0;
  const size_t off = (size_t)row * D_DIM;
  for (int j = tid; j < 512; j += 256) {
    float2 cs = tab[(size_t)t * 512 + j];
    float c = cs.x, s = cs.y;

    float a1 = bI[off + j], a2 = bI[off + 512 + j];
    float o1 = __fsub_rn(__fmul_rn(a1, c), __fmul_rn(a2, s));
    float o2 = __fadd_rn(__fmul_rn(a1, s), __fmul_rn(a2, c));
    bI[off + j] = o1; bI[off + 512 + j] = o2;
    Ih[off + j] = f32_to_bf16_rne(o1); Ih[off + 512 + j] = f32_to_bf16_rne(o2);
    ssI += (double)o1 * o1 + (double)o2 * o2;

    float p1 = bP[off + j], p2 = bP[off + 512 + j];
    float q1 = __fsub_rn(__fmul_rn(p1, c), __fmul_rn(p2, s));
    float q2 = __fadd_rn(__fmul_rn(p1, s), __fmul_rn(p2, c));
    bP[off + j] = q1; bP[off + 512 + j] = q2;
    Ph[off + j] = f32_to_bf16_rne(q1); Ph[off + 512 + j] = f32_to_bf16_rne(q2);
    ssP += (double)q1 * q1 + (double)q2 * q2;
  }
#pragma unroll
  for (int o = 32; o >= 1; o >>= 1) { ssI += __shfl_xor(ssI, o); ssP += __shfl_xor(ssP, o); }
  if ((tid & 63) == 0) { redI[tid >> 6] = ssI; redP[tid >> 6] = ssP; }
  __syncthreads();
  if (tid == 0) {
    nI[row] = fmaxf((float)sqrt(redI[0] + redI[1] + redI[2] + redI[3]), 1e-12f);
    nP[row] = fmaxf((float)sqrt(redP[0] + redP[1] + redP[2] + redP[3]), 1e-12f);
  }
}

// ---------------------------------------------------------------------------
// bf16 SCREEN for S (candidates only; exact rescore follows). (unchanged.)
// ---------------------------------------------------------------------------
__global__ void __launch_bounds__(256) screen_bf16(
    const unsigned short* __restrict__ Ih, const unsigned short* __restrict__ Ph,
    unsigned short* __restrict__ Ssc)
{
  int rem = blockIdx.x, bi = 0;
  while (rem >= (bi >> 1) + 1) { rem -= (bi >> 1) + 1; ++bi; }
  const int m0 = bi << 6, n0 = rem << 7;
  const int z = blockIdx.z;
  const unsigned short* A = Ih + (size_t)z * T_LEN * D_DIM;
  const unsigned short* B = Ph + (size_t)z * T_LEN * D_DIM;
  unsigned short* C = Ssc + (size_t)z * T_LEN * T_LEN;
  const int N = T_LEN, K = D_DIM;

  const int tid = threadIdx.x;
  const int w = tid >> 6, lane = tid & 63;
  const int kg = lane >> 4, lm = lane & 15;
  const int am0 = (w & 1) << 5;
  const int bn0 = (w >> 1) << 6;

  __shared__ unsigned short As_h[2][64][40];
  __shared__ unsigned short Bs_h[2][128][40];

  bf16x8 ones;
#pragma unroll
  for (int e = 0; e < 8; ++e) ones[e] = (short)0x3F80;

  for (int idx = tid; idx < 2048; idx += 256)
    As_h[0][idx >> 5][idx & 31] = f32_to_bf16_rne((float)(idx >> 5));
  for (int idx = tid; idx < 4096; idx += 256)
    Bs_h[0][idx >> 5][idx & 31] = f32_to_bf16_rne((float)(idx >> 5));
  __syncthreads();
  int mr[4], nc[4];
  {
    bf16x8 pa = *(const bf16x8*)&As_h[0][am0 + lm][kg << 3];
    bf16x8 pb = *(const bf16x8*)&Bs_h[0][bn0 + lm][kg << 3];
    f32x4v d1 = {0.f, 0.f, 0.f, 0.f}, d2 = {0.f, 0.f, 0.f, 0.f};
    d1 = __builtin_amdgcn_mfma_f32_16x16x32_bf16(pa, ones, d1, 0, 0, 0);
    d2 = __builtin_amdgcn_mfma_f32_16x16x32_bf16(ones, pb, d2, 0, 0, 0);
#pragma unroll
    for (int e = 0; e < 4; ++e) {
      mr[e] = ((int)d1[e]) >> 5;
      nc[e] = ((int)d2[e]) >> 5;
    }
  }
  __syncthreads();

  f32x4v c00 = {0,0,0,0}, c01 = {0,0,0,0}, c02 = {0,0,0,0}, c03 = {0,0,0,0};
  f32x4v c10 = {0,0,0,0}, c11 = {0,0,0,0}, c12 = {0,0,0,0}, c13 = {0,0,0,0};

  const int ar  = tid >> 2, ak8 = (tid & 3) << 3;
  const int bna = tid >> 2, bnb = 64 + (tid >> 2), bk8 = (tid & 3) << 3;

  bf16x8 ra, rb0, rb1;

  ra  = *(const bf16x8*)(A + (size_t)(m0 + ar) * K + ak8);
  rb0 = *(const bf16x8*)(B + (size_t)(n0 + bna) * K + bk8);
  rb1 = *(const bf16x8*)(B + (size_t)(n0 + bnb) * K + bk8);
  *(bf16x8*)&As_h[0][ar][ak8]  = ra;
  *(bf16x8*)&Bs_h[0][bna][bk8] = rb0;
  *(bf16x8*)&Bs_h[0][bnb][bk8] = rb1;
  __syncthreads();

  int buf = 0;
  for (int k0 = 0; k0 < K; k0 += 32) {
    const bool more = (k0 + 32) < K;
    if (more) {
      const int kn = k0 + 32;
      ra  = *(const bf16x8*)(A + (size_t)(m0 + ar) * K + kn + ak8);
      rb0 = *(const bf16x8*)(B + (size_t)(n0 + bna) * K + kn + bk8);
      rb1 = *(const bf16x8*)(B + (size_t)(n0 + bnb) * K + kn + bk8);
    }
    {
      bf16x8 a0 = *(const bf16x8*)&As_h[buf][am0 + lm][kg << 3];
      bf16x8 a1 = *(const bf16x8*)&As_h[buf][am0 + 16 + lm][kg << 3];
      bf16x8 b0 = *(const bf16x8*)&Bs_h[buf][bn0 + lm][kg << 3];
      bf16x8 b1 = *(const bf16x8*)&Bs_h[buf][bn0 + 16 + lm][kg << 3];
      bf16x8 b2 = *(const bf16x8*)&Bs_h[buf][bn0 + 32 + lm][kg << 3];
      bf16x8 b3 = *(const bf16x8*)&Bs_h[buf][bn0 + 48 + lm][kg << 3];
      c00 = __builtin_amdgcn_mfma_f32_16x16x32_bf16(a0, b0, c00, 0, 0, 0);
      c01 = __builtin_amdgcn_mfma_f32_16x16x32_bf16(a0, b1, c01, 0, 0, 0);
      c02 = __builtin_amdgcn_mfma_f32_16x16x32_bf16(a0, b2, c02, 0, 0, 0);
      c03 = __builtin_amdgcn_mfma_f32_16x16x32_bf16(a0, b3, c03, 0, 0, 0);
      c10 = __builtin_amdgcn_mfma_f32_16x16x32_bf16(a1, b0, c10, 0, 0, 0);
      c11 = __builtin_amdgcn_mfma_f32_16x16x32_bf16(a1, b1, c11, 0, 0, 0);
      c12 = __builtin_amdgcn_mfma_f32_16x16x32_bf16(a1, b2, c12, 0, 0, 0);
      c13 = __builtin_amdgcn_mfma_f32_16x16x32_bf16(a1, b3, c13, 0, 0, 0);
    }
    if (more) {
      const int nb = buf ^ 1;
      *(bf16x8*)&As_h[nb][ar][ak8]  = ra;
      *(bf16x8*)&Bs_h[nb][bna][bk8] = rb0;
      *(bf16x8*)&Bs_h[nb][bnb][bk8] = rb1;
    }
    __syncthreads();
    buf ^= 1;
  }

#pragma unroll
  for (int e = 0; e < 4; ++e) {
    const size_t r0 = (size_t)(m0 + mr[e]) * N;
    const size_t r1 = r0 + (size_t)16 * N;
    const int c = n0 + nc[e];
    C[r0 + c +  0] = f32_to_bf16_rne(c00[e]);
    C[r0 + c + 16] = f32_to_bf16_rne(c01[e]);
    C[r0 + c + 32] = f32_to_bf16_rne(c02[e]);
    C[r0 + c + 48] = f32_to_bf16_rne(c03[e]);
    C[r1 + c +  0] = f32_to_bf16_rne(c10[e]);
    C[r1 + c + 16] = f32_to_bf16_rne(c11[e]);
    C[r1 + c + 32] = f32_to_bf16_rne(c12[e]);
    C[r1 + c + 48] = f32_to_bf16_rne(c13[e]);
  }
}

// ---------------------------------------------------------------------------
// Top-NCAND screen candidates per causal row (bf16 S). -1 = invalid.
// ---------------------------------------------------------------------------
__global__ void __launch_bounds__(256) topk_screen(const unsigned short* __restrict__ Ssc,
                                                   int* __restrict__ cand)
{
  const int b = blockIdx.y;
  const unsigned short* S = Ssc + (size_t)b * T_LEN * T_LEN;
  const int wave = threadIdx.x >> 6, lane = threadIdx.x & 63;
  const int t = blockIdx.x * 4 + wave;
  const unsigned short* rowp = S + (size_t)t * T_LEN;
  float v[32];
#pragma unroll
  for (int i = 0; i < 32; ++i) {
    int s = lane + (i << 6);
    v[i] = (s <= t) ? bf16_to_f32(rowp[s]) : -INFINITY;
  }
  float pv = INFINITY; int pidx = -1;
  int* outp = cand + ((size_t)b * T_LEN + t) * NCAND;
  for (int k = 0; k < NCAND; ++k) {
    float bv = -INFINITY; int bi = 0x7fffffff;
#pragma unroll
    for (int i = 0; i < 32; ++i) {
      int s = lane + (i << 6);
      float vv = v[i];
      bool elig = (vv < pv) || (vv == pv && s > pidx);
      if (elig && vv > bv) { bv = vv; bi = s; }
    }
#pragma unroll
    for (int o = 32; o >= 1; o >>= 1) {
      float ov = __shfl_xor(bv, o);
      int oi = __shfl_xor(bi, o);
      if (ov > bv || (ov == bv && oi < bi)) { bv = ov; bi = oi; }
    }
    pv = bv; pidx = bi;
    if (lane == 0) outp[k] = (bi == 0x7fffffff || bv == -INFINITY) ? -1 : bi;
  }
}

// ---------------------------------------------------------------------------
// Exact rescore, MLP-RESTRUCTURED: each wave owns candidates c = wv + 4q
// (q = 0..4, static). Pointers hoisted; j OUTER (16), q INNER (5) with 5
// independent f64 accumulators -> 5x outstanding loads (r18 was serial per
// candidate: 16-load + dependent-FMA + reduce, latency-bound at 422 GB/s).
// Per-candidate j-order ascending -> f64 sums BIT-IDENTICAL to r18.
// ---------------------------------------------------------------------------
__global__ void __launch_bounds__(256) rescore_kernel(
    const float* __restrict__ I, const float* __restrict__ P,
    const int* __restrict__ cand, int* __restrict__ idx)
{
  const int row = blockIdx.x;
  const int base = row & ~(T_LEN - 1);
  const int tid = threadIdx.x;
  const int wv = tid >> 6, lane = tid & 63;

  __shared__ float valS[NCAND];
  __shared__ int   sidxS[NCAND];
  __shared__ int   candS[NCAND];

  if (tid < NCAND) candS[tid] = cand[(size_t)row * NCAND + tid];
  __syncthreads();

  double iv[16];
  const float* irow = I + (size_t)row * D_DIM;
#pragma unroll
  for (int j = 0; j < 16; ++j) iv[j] = (double)irow[lane + (j << 6)];

  // hoist 5 candidate row pointers (invalid -> row 0, masked at the end)
  const float* pr[5];
  int cs[5];
#pragma unroll
  for (int q = 0; q < 5; ++q) {
    int c = wv + (q << 2);
    int s = candS[c];
    cs[q] = s;
    pr[q] = P + ((size_t)base + (s < 0 ? 0 : s)) * D_DIM + lane;
  }

  double a0 = 0.0, a1 = 0.0, a2 = 0.0, a3 = 0.0, a4 = 0.0;
#pragma unroll
  for (int j = 0; j < 16; ++j) {
    const int o = j << 6;
    a0 = fma(iv[j], (double)pr[0][o], a0);
    a1 = fma(iv[j], (double)pr[1][o], a1);
    a2 = fma(iv[j], (double)pr[2][o], a2);
    a3 = fma(iv[j], (double)pr[3][o], a3);
    a4 = fma(iv[j], (double)pr[4][o], a4);
  }
#pragma unroll
  for (int o = 32; o >= 1; o >>= 1) {
    a0 += __shfl_xor(a0, o);
    a1 += __shfl_xor(a1, o);
    a2 += __shfl_xor(a2, o);
    a3 += __shfl_xor(a3, o);
    a4 += __shfl_xor(a4, o);
  }
  if (lane == 0) {
    double av[5] = {a0, a1, a2, a3, a4};
#pragma unroll
    for (int q = 0; q < 5; ++q) {
      int c = wv + (q << 2);
      valS[c] = (cs[q] >= 0) ? (float)(av[q] * 0.03125) : -INFINITY;
      sidxS[c] = cs[q];
    }
  }
  __syncthreads();
  if (tid == 0) {
    bool taken[NCAND];
#pragma unroll
    for (int c = 0; c < NCAND; ++c) taken[c] = false;
    int* outp = idx + (size_t)row * 16;
    for (int k = 0; k < KSEL; ++k) {
      float best = -INFINITY; int bidx = 0x7fffffff; int bc = -1;
      for (int c = 0; c < NCAND; ++c) {
        if (taken[c] || sidxS[c] < 0) continue;
        float v = valS[c];
        if (v > best || (v == best && sidxS[c] < bidx)) { best = v; bidx = sidxS[c]; bc = c; }
      }
      if (bc >= 0) { taken[bc] = true; outp[k] = bidx; }
      else outp[k] = 0;
    }
  }
}

// ---------------------------------------------------------------------------
// Wo (K x N) -> transposed bf16 hi/lo planes (N x K). After rescore (P dead).
// ---------------------------------------------------------------------------
__global__ void __launch_bounds__(256) woconvT(const float* __restrict__ Wo,
                                               unsigned short* __restrict__ HT,
                                               unsigned short* __restrict__ LT)
{
  __shared__ float tile[64][65];
  const int k0 = blockIdx.y << 6, n0 = blockIdx.x << 6;
  const int tid = threadIdx.x;
  for (int idx = tid; idx < 4096; idx += 256) {
    int r = idx >> 6, c = idx & 63;
    tile[r][c] = Wo[(size_t)(k0 + r) * D_DIM + n0 + c];
  }
  __syncthreads();
  for (int idx = tid; idx < 4096; idx += 256) {
    int n = idx >> 6, k = idx & 63;
    float v = tile[k][n];
    unsigned short h = f32_to_bf16_rne(v);
    HT[(size_t)(n0 + n) * D_DIM + k0 + k] = h;
    LT[(size_t)(n0 + n) * D_DIM + k0 + k] = f32_to_bf16_rne(v - bf16_to_f32(h));
  }
}

// ---------------------------------------------------------------------------
// Per-(b,t), WAVE-PER-ROW: gram via 4-accumulator MFMA chains + palette
// blend with swapped loops (j outer, 16 persistent accumulators). (r18.)
// ---------------------------------------------------------------------------
__global__ void __launch_bounds__(256) relmlp_kernel(
    const unsigned short* __restrict__ Ih, const unsigned short* __restrict__ Ph,
    const float* __restrict__ nI, const float* __restrict__ nP,
    const int* __restrict__ topk,
    const float* __restrict__ W1, const float* __restrict__ b1,
    const float* __restrict__ W2, const float* __restrict__ b2,
    const float* __restrict__ Wc, const float* __restrict__ bc,
    const float* __restrict__ Wm, const float* __restrict__ bm,
    const float* __restrict__ palT,
    unsigned short* __restrict__ Vh, unsigned short* __restrict__ Vl)
{
  const int wv   = threadIdx.x >> 6;          // wave id: row owner
  const int lane = threadIdx.x & 63;
  const int row  = (blockIdx.x << 2) + wv;
  const int t    = row & (T_LEN - 1);
  const int base = row & ~(T_LEN - 1);
  const int nk   = (t + 1 < KSEL) ? (t + 1) : KSEL;

  __shared__ int   sidxS[4][16];
  __shared__ float nrmS[4][16];
  __shared__ float gS[4][16][16];
  __shared__ float relS[4][KSEL][18];
  __shared__ float h1S[4][KSEL][HIDN];
  __shared__ float h2S[4][KSEL][HIDN];
  __shared__ float mixS[4][KSEL], wSS[4][KSEL], zxS[4][KSEL], zyS[4][KSEL];
  __shared__ float coefS[4][4 * KSEL];
  __shared__ int   cellS[4][4 * KSEL];

  if (lane < 16) {
    int s = t;
    if (lane >= 1) s = (lane <= nk) ? topk[(size_t)row * 16 + (lane - 1)] : 0;
    sidxS[wv][lane] = s;
    nrmS[wv][lane] = (lane == 0) ? nI[row] : nP[base + s];
  }
  __syncthreads();

  // ---- gram: direct-global MFMA fragments, 4 independent accumulators ----
  const int lm = lane & 15, kg = lane >> 4;
  {
    const unsigned short* src = (lm == 0)
        ? (Ih + (size_t)row * D_DIM)
        : (Ph + ((size_t)base + sidxS[wv][lm]) * D_DIM);
    f32x4v acc0 = {0.f, 0.f, 0.f, 0.f}, acc1 = {0.f, 0.f, 0.f, 0.f};
    f32x4v acc2 = {0.f, 0.f, 0.f, 0.f}, acc3 = {0.f, 0.f, 0.f, 0.f};
#pragma unroll
    for (int ks = 0; ks < 32; ks += 4) {
      bf16x8 a0, a1, a2, a3;
      if (lm <= nk) {
        a0 = *(const bf16x8*)(src + ((ks + 0) << 5) + (kg << 3));
        a1 = *(const bf16x8*)(src + ((ks + 1) << 5) + (kg << 3));
        a2 = *(const bf16x8*)(src + ((ks + 2) << 5) + (kg << 3));
        a3 = *(const bf16x8*)(src + ((ks + 3) << 5) + (kg << 3));
      } else {
        bf16x8 zz = {0, 0, 0, 0, 0, 0, 0, 0};
        a0 = zz; a1 = zz; a2 = zz; a3 = zz;
      }
      acc0 = __builtin_amdgcn_mfma_f32_16x16x32_bf16(a0, a0, acc0, 0, 0, 0);
      acc1 = __builtin_amdgcn_mfma_f32_16x16x32_bf16(a1, a1, acc1, 0, 0, 0);
      acc2 = __builtin_amdgcn_mfma_f32_16x16x32_bf16(a2, a2, acc2, 0, 0, 0);
      acc3 = __builtin_amdgcn_mfma_f32_16x16x32_bf16(a3, a3, acc3, 0, 0, 0);
    }
    f32x4v acc;
#pragma unroll
    for (int e = 0; e < 4; ++e)
      acc[e] = (acc0[e] + acc1[e]) + (acc2[e] + acc3[e]);

    bf16x8 pa, ones;
    unsigned short lmb = f32_to_bf16_rne((float)lm);
#pragma unroll
    for (int e = 0; e < 8; ++e) { pa[e] = (short)lmb; ones[e] = (short)0x3F80; }
    f32x4v d1 = {0.f, 0.f, 0.f, 0.f}, d2 = {0.f, 0.f, 0.f, 0.f};
    d1 = __builtin_amdgcn_mfma_f32_16x16x32_bf16(pa, ones, d1, 0, 0, 0);
    d2 = __builtin_amdgcn_mfma_f32_16x16x32_bf16(ones, pa, d2, 0, 0, 0);
#pragma unroll
    for (int e = 0; e < 4; ++e) {
      int pi2 = ((int)d1[e]) >> 5;
      int pj2 = ((int)d2[e]) >> 5;
      float g = 0.f;
      if (pi2 <= nk && pj2 <= nk) {
        g = acc[e] / (nrmS[wv][pi2] * nrmS[wv][pj2]);
        g = fminf(fmaxf(g, -1.f), 1.f);
      }
      gS[wv][pi2][pj2] = g;
    }
  }
  __syncthreads();

  // ---- rel features ----
  for (int o = lane; o < KSEL * 17; o += 64) {
    int k = o / 17, f = o % 17;
    float v = 0.f;
    if (k < nk) {
      if (f < KSEL)        v = (f < nk) ? gS[wv][k + 1][f + 1] : 0.f;
      else if (f == KSEL)  v = gS[wv][0][k + 1];
      else                 v = (float)(t - sidxS[wv][k + 1]) * (1.0f / (float)T_LEN);
    }
    relS[wv][k][f] = v;
  }
  __syncthreads();

  // ---- MLP1: lane = output channel m ----
#pragma unroll
  for (int k = 0; k < KSEL; ++k) {
    float a = b1[lane];
#pragma unroll
    for (int f = 0; f < 17; ++f) a = fmaf(relS[wv][k][f], W1[f * HIDN + lane], a);
    h1S[wv][k][lane] = geluf(a);
  }
  __syncthreads();

  // ---- MLP2 ----
#pragma unroll
  for (int k = 0; k < KSEL; ++k) {
    float a = b2[lane];
#pragma unroll 8
    for (int n = 0; n < HIDN; ++n) a = fmaf(h1S[wv][k][n], W2[n * HIDN + lane], a);
    h2S[wv][k][lane] = geluf(a);
  }
  __syncthreads();

  // ---- heads ----
  if (lane < KSEL) {
    float a0 = 0.f, a1 = 0.f, am = 0.f;
#pragma unroll 8
    for (int n = 0; n < HIDN; ++n) {
      float h = h2S[wv][lane][n];
      a0 = fmaf(h, Wc[n * 2 + 0], a0);
      a1 = fmaf(h, Wc[n * 2 + 1], a1);
      am = fmaf(h, Wm[n], am);
    }
    zxS[wv][lane] = tanhf(a0 + bc[0]);
    zyS[wv][lane] = tanhf(a1 + bc[1]);
    mixS[wv][lane] = am + bm[0];
  }
  __syncthreads();

  // ---- softmax (lane 0 of each wave) ----
  if (lane == 0) {
    float mx = -INFINITY;
    for (int k = 0; k < nk; ++k) mx = fmaxf(mx, mixS[wv][k]);
    float ssum = 0.f;
    for (int k = 0; k < nk; ++k) { float e = expf(mixS[wv][k] - mx); wSS[wv][k] = e; ssum += e; }
    float inv = 1.f / ssum;
    for (int k = 0; k < nk; ++k) wSS[wv][k] *= inv;
  }
  __syncthreads();

  // ---- bilinear coefficients ----
  if (lane < KSEL) {
    int k = lane;
    if (k < nk) {
      float w = wSS[wv][k];
      float fx = fminf(fmaxf((zxS[wv][k] + 1.f) * 0.5f * 15.f, 0.f), 15.f);
      float fy = fminf(fmaxf((zyS[wv][k] + 1.f) * 0.5f * 15.f, 0.f), 15.f);
      int x0 = (int)floorf(fx); int x1i = (x0 + 1 < 15) ? x0 + 1 : 15;
      int y0 = (int)floorf(fy); int y1i = (y0 + 1 < 15) ? y0 + 1 : 15;
      float wx = fx - (float)x0, wy = fy - (float)y0;
      cellS[wv][k * 4 + 0] = y0 * 16 + x0;   coefS[wv][k * 4 + 0] = w * (1.f - wy) * (1.f - wx);
      cellS[wv][k * 4 + 1] = y0 * 16 + x1i;  coefS[wv][k * 4 + 1] = w * (1.f - wy) * wx;
      cellS[wv][k * 4 + 2] = y1i * 16 + x0;  coefS[wv][k * 4 + 2] = w * wy * (1.f - wx);
      cellS[wv][k * 4 + 3] = y1i * 16 + x1i; coefS[wv][k * 4 + 3] = w * wy * wx;
    } else {
      cellS[wv][k * 4 + 0] = cellS[wv][k * 4 + 1] = cellS[wv][k * 4 + 2] = cellS[wv][k * 4 + 3] = 0;
      coefS[wv][k * 4 + 0] = coefS[wv][k * 4 + 1] = coefS[wv][k * 4 + 2] = coefS[wv][k * 4 + 3] = 0.f;
    }
  }
  __syncthreads();

  // ---- palette blend: j OUTER (runtime 60), d INNER (16 accumulators) ----
  {
    float av[16];
#pragma unroll
    for (int e = 0; e < 16; ++e) av[e] = 0.f;
    const int nj = 4 * nk;
    for (int j = 0; j < nj; ++j) {
      const float cf = coefS[wv][j];
      const float* prow = palT + (size_t)cellS[wv][j] * D_DIM + lane;
#pragma unroll
      for (int e = 0; e < 16; ++e)
        av[e] = fmaf(cf, prow[e << 6], av[e]);
    }
#pragma unroll
    for (int e = 0; e < 16; ++e) {
      const int d = lane + (e << 6);
      float a = av[e];
      unsigned short h = f32_to_bf16_rne(a);
      Vh[(size_t)row * D_DIM + d] = h;
      Vl[(size_t)row * D_DIM + d] = f32_to_bf16_rne(a - bf16_to_f32(h));
    }
  }
}

// ---------------------------------------------------------------------------
// Split-bf16 MFMA GEMM for out = V @ Wo. (r10, unchanged.)
// ---------------------------------------------------------------------------
__global__ void __launch_bounds__(256) gemmbf(
    const unsigned short* __restrict__ Ah, const unsigned short* __restrict__ Al,
    const unsigned short* __restrict__ BhT, const unsigned short* __restrict__ BlT,
    float* __restrict__ C, int N, int K)
{
  const int m0 = blockIdx.y << 6, n0 = blockIdx.x << 7;
  const int tid = threadIdx.x;
  const int w = tid >> 6, lane = tid & 63;
  const int kg = lane >> 4, lm = lane & 15;
  const int am0 = (w & 1) << 5;
  const int bn0 = (w >> 1) << 6;

  __shared__ unsigned short As_h[2][64][40],  As_l[2][64][40];
  __shared__ unsigned short Bs_h[2][128][40], Bs_l[2][128][40];

  bf16x8 ones;
#pragma unroll
  for (int e = 0; e < 8; ++e) ones[e] = (short)0x3F80;

  for (int idx = tid; idx < 2048; idx += 256)
    As_h[0][idx >> 5][idx & 31] = f32_to_bf16_rne((float)(idx >> 5));
  for (int idx = tid; idx < 4096; idx += 256)
    Bs_h[0][idx >> 5][idx & 31] = f32_to_bf16_rne((float)(idx >> 5));
  __syncthreads();
  int mr[4], nc[4];
  {
    bf16x8 pa = *(const bf16x8*)&As_h[0][am0 + lm][kg << 3];
    bf16x8 pb = *(const bf16x8*)&Bs_h[0][bn0 + lm][kg << 3];
    f32x4v d1 = {0.f, 0.f, 0.f, 0.f}, d2 = {0.f, 0.f, 0.f, 0.f};
    d1 = __builtin_amdgcn_mfma_f32_16x16x32_bf16(pa, ones, d1, 0, 0, 0);
    d2 = __builtin_amdgcn_mfma_f32_16x16x32_bf16(ones, pb, d2, 0, 0, 0);
#pragma unroll
    for (int e = 0; e < 4; ++e) {
      mr[e] = ((int)d1[e]) >> 5;
      nc[e] = ((int)d2[e]) >> 5;
    }
  }
  __syncthreads();

  f32x4v c00 = {0,0,0,0}, c01 = {0,0,0,0}, c02 = {0,0,0,0}, c03 = {0,0,0,0};
  f32x4v c10 = {0,0,0,0}, c11 = {0,0,0,0}, c12 = {0,0,0,0}, c13 = {0,0,0,0};

  const int ar  = tid >> 2, ak8 = (tid & 3) << 3;
  const int bna = tid >> 2, bnb = 64 + (tid >> 2), bk8 = (tid & 3) << 3;

  bf16x8 rah, ral, rbh0, rbl0, rbh1, rbl1;

  rah  = *(const bf16x8*)(Ah  + (size_t)(m0 + ar) * K + ak8);
  ral  = *(const bf16x8*)(Al  + (size_t)(m0 + ar) * K + ak8);
  rbh0 = *(const bf16x8*)(BhT + (size_t)(n0 + bna) * K + bk8);
  rbl0 = *(const bf16x8*)(BlT + (size_t)(n0 + bna) * K + bk8);
  rbh1 = *(const bf16x8*)(BhT + (size_t)(n0 + bnb) * K + bk8);
  rbl1 = *(const bf16x8*)(BlT + (size_t)(n0 + bnb) * K + bk8);
  *(bf16x8*)&As_h[0][ar][ak8]  = rah;
  *(bf16x8*)&As_l[0][ar][ak8]  = ral;
  *(bf16x8*)&Bs_h[0][bna][bk8] = rbh0;
  *(bf16x8*)&Bs_l[0][bna][bk8] = rbl0;
  *(bf16x8*)&Bs_h[0][bnb][bk8] = rbh1;
  *(bf16x8*)&Bs_l[0][bnb][bk8] = rbl1;
  __syncthreads();

  int buf = 0;
  for (int k0 = 0; k0 < K; k0 += 32) {
    const bool more = (k0 + 32) < K;
    if (more) {
      const int kn = k0 + 32;
      rah  = *(const bf16x8*)(Ah  + (size_t)(m0 + ar) * K + kn + ak8);
      ral  = *(const bf16x8*)(Al  + (size_t)(m0 + ar) * K + kn + ak8);
      rbh0 = *(const bf16x8*)(BhT + (size_t)(n0 + bna) * K + kn + bk8);
      rbl0 = *(const bf16x8*)(BlT + (size_t)(n0 + bna) * K + kn + bk8);
      rbh1 = *(const bf16x8*)(BhT + (size_t)(n0 + bnb) * K + kn + bk8);
      rbl1 = *(const bf16x8*)(BlT + (size_t)(n0 + bnb) * K + kn + bk8);
    }
    {
      bf16x8 ah0 = *(const bf16x8*)&As_h[buf][am0 + lm][kg << 3];
      bf16x8 ah1 = *(const bf16x8*)&As_h[buf][am0 + 16 + lm][kg << 3];
      bf16x8 al0 = *(const bf16x8*)&As_l[buf][am0 + lm][kg << 3];
      bf16x8 al1 = *(const bf16x8*)&As_l[buf][am0 + 16 + lm][kg << 3];
      bf16x8 bh0 = *(const bf16x8*)&Bs_h[buf][bn0 + lm][kg << 3];
      bf16x8 bh1 = *(const bf16x8*)&Bs_h[buf][bn0 + 16 + lm][kg << 3];
      bf16x8 bh2 = *(const bf16x8*)&Bs_h[buf][bn0 + 32 + lm][kg << 3];
      bf16x8 bh3 = *(const bf16x8*)&Bs_h[buf][bn0 + 48 + lm][kg << 3];
      bf16x8 bl0 = *(const bf16x8*)&Bs_l[buf][bn0 + lm][kg << 3];
      bf16x8 bl1 = *(const bf16x8*)&Bs_l[buf][bn0 + 16 + lm][kg << 3];
      bf16x8 bl2 = *(const bf16x8*)&Bs_l[buf][bn0 + 32 + lm][kg << 3];
      bf16x8 bl3 = *(const bf16x8*)&Bs_l[buf][bn0 + 48 + lm][kg << 3];

      c00 = __builtin_amdgcn_mfma_f32_16x16x32_bf16(ah0, bh0, c00, 0, 0, 0);
      c01 = __builtin_amdgcn_mfma_f32_16x16x32_bf16(ah0, bh1, c01, 0, 0, 0);
      c02 = __builtin_amdgcn_mfma_f32_16x16x32_bf16(ah0, bh2, c02, 0, 0, 0);
      c03 = __builtin_amdgcn_mfma_f32_16x16x32_bf16(ah0, bh3, c03, 0, 0, 0);
      c10 = __builtin_amdgcn_mfma_f32_16x16x32_bf16(ah1, bh0, c10, 0, 0, 0);
      c11 = __builtin_amdgcn_mfma_f32_16x16x32_bf16(ah1, bh1, c11, 0, 0, 0);
      c12 = __builtin_amdgcn_mfma_f32_16x16x32_bf16(ah1, bh2, c12, 0, 0, 0);
      c13 = __builtin_amdgcn_mfma_f32_16x16x32_bf16(ah1, bh3, c13, 0, 0, 0);

      c00 = __builtin_amdgcn_mfma_f32_16x16x32_bf16(ah0, bl0, c00, 0, 0, 0);
      c01 = __builtin_amdgcn_mfma_f32_16x16x32_bf16(ah0, bl1, c01, 0, 0, 0);
      c02 = __builtin_amdgcn_mfma_f32_16x16x32_bf16(ah0, bl2, c02, 0, 0, 0);
      c03 = __builtin_amdgcn_mfma_f32_16x16x32_bf16(ah0, bl3, c03, 0, 0, 0);
      c10 = __builtin_amdgcn_mfma_f32_16x16x32_bf16(ah1, bl0, c10, 0, 0, 0);
      c11 = __builtin_amdgcn_mfma_f32_16x16x32_bf16(ah1, bl1, c11, 0, 0, 0);
      c12 = __builtin_amdgcn_mfma_f32_16x16x32_bf16(ah1, bl2, c12, 0, 0, 0);
      c13 = __builtin_amdgcn_mfma_f32_16x16x32_bf16(ah1, bl3, c13, 0, 0, 0);

      c00 = __builtin_amdgcn_mfma_f32_16x16x32_bf16(al0, bh0, c00, 0, 0, 0);
      c01 = __builtin_amdgcn_mfma_f32_16x16x32_bf16(al0, bh1, c01, 0, 0, 0);
      c02 = __builtin_amdgcn_mfma_f32_16x16x32_bf16(al0, bh2, c02, 0, 0, 0);
      c03 = __builtin_amdgcn_mfma_f32_16x16x32_bf16(al0, bh3, c03, 0, 0, 0);
      c10 = __builtin_amdgcn_mfma_f32_16x16x32_bf16(al1, bh0, c10, 0, 0, 0);
      c11 = __builtin_amdgcn_mfma_f32_16x16x32_bf16(al1, bh1, c11, 0, 0, 0);
      c12 = __builtin_amdgcn_mfma_f32_16x16x32_bf16(al1, bh2, c12, 0, 0, 0);
      c13 = __builtin_amdgcn_mfma_f32_16x16x32_bf16(al1, bh3, c13, 0, 0, 0);
    }
    if (more) {
      const int nb = buf ^ 1;
      *(bf16x8*)&As_h[nb][ar][ak8]  = rah;
      *(bf16x8*)&As_l[nb][ar][ak8]  = ral;
      *(bf16x8*)&Bs_h[nb][bna][bk8] = rbh0;
      *(bf16x8*)&Bs_l[nb][bna][bk8] = rbl0;
      *(bf16x8*)&Bs_h[nb][bnb][bk8] = rbh1;
      *(bf16x8*)&Bs_l[nb][bnb][bk8] = rbl1;
    }
    __syncthreads();
    buf ^= 1;
  }

#pragma unroll
  for (int e = 0; e < 4; ++e) {
    const size_t r0 = (size_t)(m0 + mr[e]) * N;
    const size_t r1 = r0 + (size_t)16 * N;
    const int c = n0 + nc[e];
    C[r0 + c +  0] = c00[e];
    C[r0 + c + 16] = c01[e];
    C[r0 + c + 32] = c02[e];
    C[r0 + c + 48] = c03[e];
    C[r1 + c +  0] = c10[e];
    C[r1 + c + 16] = c11[e];
    C[r1 + c + 32] = c12[e];
    C[r1 + c + 48] = c13[e];
  }
}

// ---------------------------------------------------------------------------
// Host launcher. (r18 structure, unchanged.)
// ---------------------------------------------------------------------------
extern "C" void kernel_launch(void* const* d_in, const int* in_sizes, int n_in,
                              void* d_out, int out_size, void* d_ws, size_t ws_size,
                              hipStream_t stream)
{
  (void)in_sizes; (void)n_in; (void)out_size; (void)ws_size;
  const float* x   = (const float*)d_in[0];
  const float* Wi  = (const float*)d_in[1];
  const float* Wp  = (const float*)d_in[2];
  const float* pal = (const float*)d_in[3];
  const float* W1  = (const float*)d_in[4];
  const float* b1  = (const float*)d_in[5];
  const float* W2  = (const float*)d_in[6];
  const float* b2  = (const float*)d_in[7];
  const float* Wc  = (const float*)d_in[8];
  const float* bc  = (const float*)d_in[9];
  const float* Wm  = (const float*)d_in[10];
  const float* bm  = (const float*)d_in[11];
  const float* Wo  = (const float*)d_in[12];
  float* out = (float*)d_out;

  float* w = (float*)d_ws;
  float* palT = w;  w += (size_t)256 * D_DIM;
  float* I    = w;  w += (size_t)BATCH * T_LEN * D_DIM;
  float* P    = w;  w += (size_t)BATCH * T_LEN * D_DIM;
  float* Sb   = w;  w += (size_t)BATCH * T_LEN * T_LEN;
  float* nIb  = w;  w += (size_t)BATCH * T_LEN;
  float* nPb  = w;  w += (size_t)BATCH * T_LEN;
  int*   idx  = (int*)w;  w += (size_t)BATCH * T_LEN * 16;
  int*   cand = (int*)w;

  unsigned short* Xh = (unsigned short*)Sb;
  unsigned short* Xm = Xh + (size_t)4096 * 1024;
  unsigned short* Xl = Xm + (size_t)4096 * 1024;
  unsigned short* WT = (unsigned short*)d_out;

  float2* tab = (float2*)Sb;
  unsigned short* Ssc = (unsigned short*)Sb;
  unsigned short* Ih  = (unsigned short*)(Sb + (size_t)4 * 1024 * 1024);
  unsigned short* Ph  = Ih + (size_t)4 * 1024 * 1024;
  unsigned short* Vh  = (unsigned short*)Sb;
  unsigned short* Vl  = Vh + (size_t)4 * 1024 * 1024;
  unsigned short* WohT = (unsigned short*)P;
  unsigned short* WolT = WohT + (size_t)D_DIM * D_DIM;

  const int MROWS = BATCH * T_LEN;  // 4096

  xsplit3<<<(MROWS * D_DIM) / (256 * 4), 256, 0, stream>>>(x, Xh, Xm, Xl);
  wsplit3T<<<dim3(D_DIM / 64, D_DIM / 64, 2), 256, 0, stream>>>(Wi, Wp, WT);

  gemm3bf<<<dim3(D_DIM / 64, MROWS / 64, 2), 256, 0, stream>>>(
      Xh, Xm, Xl, WT, I);

  prep_kernel<<<T_LEN + 1024, 256, 0, stream>>>(tab, pal, palT);

  rope_norm_kernel<<<MROWS, 256, 0, stream>>>(I, P, tab, nIb, nPb, Ih, Ph);

  screen_bf16<<<dim3(272, 1, 2), 256, 0, stream>>>(Ih, Ph, Ssc);

  topk_screen<<<dim3(T_LEN / 4, BATCH), 256, 0, stream>>>(Ssc, cand);

  rescore_kernel<<<MROWS, 256, 0, stream>>>(I, P, cand, idx);

  woconvT<<<dim3(D_DIM / 64, D_DIM / 64), 256, 0, stream>>>(Wo, WohT, WolT);

  relmlp_kernel<<<MROWS / 4, 256, 0, stream>>>(Ih, Ph, nIb, nPb, idx,
                                               W1, b1, W2, b2, Wc, bc, Wm, bm,
                                               palT, Vh, Vl);

  gemmbf<<<dim3(D_DIM / 128, MROWS / 64), 256, 0, stream>>>(
      Vh, Vl, WohT, WolT, out, D_DIM, D_DIM);
}